// Round 2
// baseline (1014.963 us; speedup 1.0000x reference)
//
#include <hip/hip_runtime.h>
#include <hip/hip_bf16.h>

#define NGRAPHS 64

// ---------------- degree accumulation ----------------
__global__ void k_degrees(const int* __restrict__ src, const int* __restrict__ dst,
                          float* __restrict__ deg_in, float* __restrict__ deg_out, int E) {
    int e = blockIdx.x * 256 + threadIdx.x;
    if (e < E) {
        atomicAdd(&deg_in[dst[e]], 1.0f);
        atomicAdd(&deg_out[src[e]], 1.0f);
    }
}

// ---------------- norms ----------------
__global__ void k_norms(const float* __restrict__ deg_in, const float* __restrict__ deg_out,
                        float* __restrict__ norm_src, float* __restrict__ norm_dst, int n) {
    int i = blockIdx.x * 256 + threadIdx.x;
    if (i < n) {
        norm_src[i] = rsqrtf(fmaxf(deg_out[i], 1.0f));
        norm_dst[i] = rsqrtf(fmaxf(deg_in[i], 1.0f));
    }
}

// ---------------- layer-0 scalar scatter: agg0[dst] += in_deg[src]*norm_src[src] ----------------
__global__ void k_scatter0(const float* __restrict__ deg_in, const float* __restrict__ norm_src,
                           const int* __restrict__ src, const int* __restrict__ dst,
                           float* __restrict__ agg0, int E) {
    int e = blockIdx.x * 256 + threadIdx.x;
    if (e < E) {
        int s = src[e];
        atomicAdd(&agg0[dst[e]], deg_in[s] * norm_src[s]);
    }
}

// ---------------- layer-0 dense: h[i][j] = relu(agg0[i]*norm_dst[i]*W0[j]+b0[j]) * norm_src[i] ----------------
__global__ void k_dense0(const float* __restrict__ agg0, const float* __restrict__ norm_dst,
                         const float* __restrict__ norm_src,
                         const float* __restrict__ W0, const float* __restrict__ b0,
                         float* __restrict__ out, int n) {
    int local = threadIdx.x >> 6, j = threadIdx.x & 63;
    int i = blockIdx.x * 4 + local;
    if (i < n) {
        float v = agg0[i] * norm_dst[i] * W0[j] + b0[j];
        v = fmaxf(v, 0.0f) * norm_src[i];
        out[(size_t)i * 64 + j] = v;
    }
}

// ---------------- 64-wide edge scatter: agg[dst][j] += h[src][j] (h pre-scaled by norm_src) ----------------
__global__ void k_scatter64(const float* __restrict__ h, const int* __restrict__ src,
                            const int* __restrict__ dst, float* __restrict__ agg, int E) {
    int e = blockIdx.x * 4 + (threadIdx.x >> 6);
    int j = threadIdx.x & 63;
    if (e < E) {
        int s = src[e], d = dst[e];
        atomicAdd(&agg[(size_t)d * 64 + j], h[(size_t)s * 64 + j]);
    }
}

// ---------------- dense 64x64: out[i][:] = relu((agg[i]*norm_dst[i]) @ W + b) [* norm_src[i]] ----------------
__global__ void k_dense64(const float* __restrict__ agg, const float* __restrict__ norm_dst,
                          const float* __restrict__ scale_out,  // nullptr => no output scaling
                          const float* __restrict__ W, const float* __restrict__ b,
                          float* __restrict__ out, int n) {
    __shared__ float Ws[64 * 64];
    __shared__ float bs[64];
    __shared__ float arow[4][64];
    int tid = threadIdx.x;
    #pragma unroll
    for (int it = 0; it < 16; ++it) {
        int idx = tid + it * 256;
        Ws[idx] = W[idx];
    }
    if (tid < 64) bs[tid] = b[tid];
    int local = tid >> 6, j = tid & 63;
    int i = blockIdx.x * 4 + local;
    if (i < n) arow[local][j] = agg[(size_t)i * 64 + j] * norm_dst[i];
    __syncthreads();
    if (i >= n) return;
    float acc = bs[j];
    #pragma unroll
    for (int k = 0; k < 64; ++k) acc = fmaf(arow[local][k], Ws[k * 64 + j], acc);
    acc = fmaxf(acc, 0.0f);
    if (scale_out) acc *= scale_out[i];
    out[(size_t)i * 64 + j] = acc;
}

// ---------------- readout: per-node dot(h, Wr) -> per-graph sum + count ----------------
__global__ void k_readout(const float* __restrict__ h, const int* __restrict__ n2g,
                          const float* __restrict__ Wr,
                          float* __restrict__ gsum, float* __restrict__ gcnt, int n) {
    int i = blockIdx.x * 4 + (threadIdx.x >> 6);
    int j = threadIdx.x & 63;
    if (i >= n) return;
    float v = h[(size_t)i * 64 + j] * Wr[j];
    #pragma unroll
    for (int off = 32; off > 0; off >>= 1) v += __shfl_down(v, off);
    if (j == 0) {
        int g = n2g[i];
        atomicAdd(&gsum[g], v);
        atomicAdd(&gcnt[g], 1.0f);
    }
}

// ---------------- finalize: out[g] = gsum/max(gcnt,1) + br ----------------
__global__ void k_finalize(const float* __restrict__ gsum, const float* __restrict__ gcnt,
                           const float* __restrict__ br, float* __restrict__ out) {
    int g = threadIdx.x;
    out[g] = gsum[g] / fmaxf(gcnt[g], 1.0f) + br[0];
}

extern "C" void kernel_launch(void* const* d_in, const int* in_sizes, int n_in,
                              void* d_out, int out_size, void* d_ws, size_t ws_size,
                              hipStream_t stream) {
    const int* src = (const int*)d_in[0];
    const int* dst = (const int*)d_in[1];
    const int* n2g = (const int*)d_in[2];
    const float* W0 = (const float*)d_in[3];
    const float* b0 = (const float*)d_in[4];
    const float* W1 = (const float*)d_in[5];
    const float* b1 = (const float*)d_in[6];
    const float* W2 = (const float*)d_in[7];
    const float* b2 = (const float*)d_in[8];
    const float* Wr = (const float*)d_in[9];
    const float* br = (const float*)d_in[10];
    float* out = (float*)d_out;

    int E = in_sizes[0];
    int n = in_sizes[2];

    // Workspace layout (floats):
    // [deg_in n][deg_out n][agg0 n][gsum 64][gcnt 64][norm_src n][norm_dst n][hA 64n][aggB 64n]
    float* p = (float*)d_ws;
    float* deg_in = p;
    float* deg_out = deg_in + n;
    float* agg0 = deg_out + n;
    float* gsum = agg0 + n;
    float* gcnt = gsum + NGRAPHS;
    float* norm_src = gcnt + NGRAPHS;
    float* norm_dst = norm_src + n;
    float* hA = norm_dst + n;
    float* aggB = hA + (size_t)n * 64;

    // zero: deg_in, deg_out, agg0, gsum, gcnt (contiguous region)
    hipMemsetAsync(deg_in, 0, ((size_t)3 * n + 2 * NGRAPHS) * sizeof(float), stream);

    k_degrees<<<(E + 255) / 256, 256, 0, stream>>>(src, dst, deg_in, deg_out, E);
    k_norms<<<(n + 255) / 256, 256, 0, stream>>>(deg_in, deg_out, norm_src, norm_dst, n);
    k_scatter0<<<(E + 255) / 256, 256, 0, stream>>>(deg_in, norm_src, src, dst, agg0, E);
    k_dense0<<<(n + 3) / 4, 256, 0, stream>>>(agg0, norm_dst, norm_src, W0, b0, hA, n);

    hipMemsetAsync(aggB, 0, (size_t)n * 64 * sizeof(float), stream);
    k_scatter64<<<(E + 3) / 4, 256, 0, stream>>>(hA, src, dst, aggB, E);
    k_dense64<<<(n + 3) / 4, 256, 0, stream>>>(aggB, norm_dst, norm_src, W1, b1, hA, n);

    hipMemsetAsync(aggB, 0, (size_t)n * 64 * sizeof(float), stream);
    k_scatter64<<<(E + 3) / 4, 256, 0, stream>>>(hA, src, dst, aggB, E);
    k_dense64<<<(n + 3) / 4, 256, 0, stream>>>(aggB, norm_dst, nullptr, W2, b2, hA, n);

    k_readout<<<(n + 3) / 4, 256, 0, stream>>>(hA, n2g, Wr, gsum, gcnt, n);
    k_finalize<<<1, 64, 0, stream>>>(gsum, gcnt, br, out);
}

// Round 3
// 675.083 us; speedup vs baseline: 1.5035x; 1.5035x over previous
//
#include <hip/hip_runtime.h>
#include <hip/hip_bf16.h>

#define NGRAPHS 64

// ---------------- degree accumulation ----------------
__global__ void k_degrees(const int* __restrict__ src, const int* __restrict__ dst,
                          float* __restrict__ deg_in, float* __restrict__ deg_out, int E) {
    int e = blockIdx.x * 256 + threadIdx.x;
    if (e < E) {
        atomicAdd(&deg_in[dst[e]], 1.0f);
        atomicAdd(&deg_out[src[e]], 1.0f);
    }
}

// ---------------- norms ----------------
__global__ void k_norms(const float* __restrict__ deg_in, const float* __restrict__ deg_out,
                        float* __restrict__ norm_src, float* __restrict__ norm_dst, int n) {
    int i = blockIdx.x * 256 + threadIdx.x;
    if (i < n) {
        norm_src[i] = rsqrtf(fmaxf(deg_out[i], 1.0f));
        norm_dst[i] = rsqrtf(fmaxf(deg_in[i], 1.0f));
    }
}

// ---------------- layer-0 scalar scatter: agg0[dst] += in_deg[src]*norm_src[src] ----------------
__global__ void k_scatter0(const float* __restrict__ deg_in, const float* __restrict__ norm_src,
                           const int* __restrict__ src, const int* __restrict__ dst,
                           float* __restrict__ agg0, int E) {
    int e = blockIdx.x * 256 + threadIdx.x;
    if (e < E) {
        int s = src[e];
        atomicAdd(&agg0[dst[e]], deg_in[s] * norm_src[s]);
    }
}

// ---------------- layer-0 dense: h[i][j] = relu(agg0[i]*norm_dst[i]*W0[j]+b0[j]) * norm_src[i] ----------------
__global__ void k_dense0(const float* __restrict__ agg0, const float* __restrict__ norm_dst,
                         const float* __restrict__ norm_src,
                         const float* __restrict__ W0, const float* __restrict__ b0,
                         float* __restrict__ out, int n) {
    int local = threadIdx.x >> 6, j = threadIdx.x & 63;
    int i = blockIdx.x * 4 + local;
    if (i < n) {
        float v = agg0[i] * norm_dst[i] * W0[j] + b0[j];
        v = fmaxf(v, 0.0f) * norm_src[i];
        out[(size_t)i * 64 + j] = v;
    }
}

// ---------------- 64-wide edge scatter: agg[dst][j] += h[src][j] (h pre-scaled by norm_src) ----------------
__global__ void k_scatter64(const float* __restrict__ h, const int* __restrict__ src,
                            const int* __restrict__ dst, float* __restrict__ agg, int E) {
    int e = blockIdx.x * 4 + (threadIdx.x >> 6);
    int j = threadIdx.x & 63;
    if (e < E) {
        int s = src[e], d = dst[e];
        atomicAdd(&agg[(size_t)d * 64 + j], h[(size_t)s * 64 + j]);
    }
}

// ---------------- dense 64x64: out[i][:] = relu((agg[i]*norm_dst[i]) @ W + b) [* norm_src[i]] ----------------
__global__ void k_dense64(const float* __restrict__ agg, const float* __restrict__ norm_dst,
                          const float* __restrict__ scale_out,  // nullptr => no output scaling
                          const float* __restrict__ W, const float* __restrict__ b,
                          float* __restrict__ out, int n) {
    __shared__ float Ws[64 * 64];
    __shared__ float bs[64];
    __shared__ float arow[4][64];
    int tid = threadIdx.x;
    #pragma unroll
    for (int it = 0; it < 16; ++it) {
        int idx = tid + it * 256;
        Ws[idx] = W[idx];
    }
    if (tid < 64) bs[tid] = b[tid];
    int local = tid >> 6, j = tid & 63;
    int i = blockIdx.x * 4 + local;
    if (i < n) arow[local][j] = agg[(size_t)i * 64 + j] * norm_dst[i];
    __syncthreads();
    if (i >= n) return;
    float acc = bs[j];
    #pragma unroll
    for (int k = 0; k < 64; ++k) acc = fmaf(arow[local][k], Ws[k * 64 + j], acc);
    acc = fmaxf(acc, 0.0f);
    if (scale_out) acc *= scale_out[i];
    out[(size_t)i * 64 + j] = acc;
}

// ---------------- per-node dot(h[i], Wr) -> r[i]  (no atomics) ----------------
__global__ void k_dot(const float* __restrict__ h, const float* __restrict__ Wr,
                      float* __restrict__ r, int n) {
    int i = blockIdx.x * 4 + (threadIdx.x >> 6);
    int j = threadIdx.x & 63;
    if (i >= n) return;
    float v = h[(size_t)i * 64 + j] * Wr[j];
    #pragma unroll
    for (int off = 32; off > 0; off >>= 1) v += __shfl_down(v, off);
    if (j == 0) r[i] = v;
}

// ---------------- per-graph mean: block g sums r[i] where n2g[i]==g  (no atomics) ----------------
__global__ void k_graphmean(const float* __restrict__ r, const int* __restrict__ n2g,
                            const float* __restrict__ br, float* __restrict__ out, int n) {
    __shared__ float ssum[4], scnt[4];
    int g = blockIdx.x;
    int tid = threadIdx.x;
    float s = 0.0f, c = 0.0f;
    for (int i = tid; i < n; i += 256) {
        bool m = (n2g[i] == g);
        if (m) { s += r[i]; c += 1.0f; }
    }
    #pragma unroll
    for (int off = 32; off > 0; off >>= 1) {
        s += __shfl_down(s, off);
        c += __shfl_down(c, off);
    }
    int wave = tid >> 6;
    if ((tid & 63) == 0) { ssum[wave] = s; scnt[wave] = c; }
    __syncthreads();
    if (tid == 0) {
        float S = ssum[0] + ssum[1] + ssum[2] + ssum[3];
        float C = scnt[0] + scnt[1] + scnt[2] + scnt[3];
        out[g] = S / fmaxf(C, 1.0f) + br[0];
    }
}

extern "C" void kernel_launch(void* const* d_in, const int* in_sizes, int n_in,
                              void* d_out, int out_size, void* d_ws, size_t ws_size,
                              hipStream_t stream) {
    const int* src = (const int*)d_in[0];
    const int* dst = (const int*)d_in[1];
    const int* n2g = (const int*)d_in[2];
    const float* W0 = (const float*)d_in[3];
    const float* b0 = (const float*)d_in[4];
    const float* W1 = (const float*)d_in[5];
    const float* b1 = (const float*)d_in[6];
    const float* W2 = (const float*)d_in[7];
    const float* b2 = (const float*)d_in[8];
    const float* Wr = (const float*)d_in[9];
    const float* br = (const float*)d_in[10];
    float* out = (float*)d_out;

    int E = in_sizes[0];
    int n = in_sizes[2];

    // Workspace layout (floats):
    // [deg_in n][deg_out n][agg0 n][r n][norm_src n][norm_dst n][hA 64n][aggB 64n]
    float* p = (float*)d_ws;
    float* deg_in = p;
    float* deg_out = deg_in + n;
    float* agg0 = deg_out + n;
    float* r = agg0 + n;
    float* norm_src = r + n;
    float* norm_dst = norm_src + n;
    float* hA = norm_dst + n;
    float* aggB = hA + (size_t)n * 64;

    // zero: deg_in, deg_out, agg0 (contiguous region)
    hipMemsetAsync(deg_in, 0, (size_t)3 * n * sizeof(float), stream);

    k_degrees<<<(E + 255) / 256, 256, 0, stream>>>(src, dst, deg_in, deg_out, E);
    k_norms<<<(n + 255) / 256, 256, 0, stream>>>(deg_in, deg_out, norm_src, norm_dst, n);
    k_scatter0<<<(E + 255) / 256, 256, 0, stream>>>(deg_in, norm_src, src, dst, agg0, E);
    k_dense0<<<(n + 3) / 4, 256, 0, stream>>>(agg0, norm_dst, norm_src, W0, b0, hA, n);

    hipMemsetAsync(aggB, 0, (size_t)n * 64 * sizeof(float), stream);
    k_scatter64<<<(E + 3) / 4, 256, 0, stream>>>(hA, src, dst, aggB, E);
    k_dense64<<<(n + 3) / 4, 256, 0, stream>>>(aggB, norm_dst, norm_src, W1, b1, hA, n);

    hipMemsetAsync(aggB, 0, (size_t)n * 64 * sizeof(float), stream);
    k_scatter64<<<(E + 3) / 4, 256, 0, stream>>>(hA, src, dst, aggB, E);
    k_dense64<<<(n + 3) / 4, 256, 0, stream>>>(aggB, norm_dst, nullptr, W2, b2, hA, n);

    k_dot<<<(n + 3) / 4, 256, 0, stream>>>(hA, Wr, r, n);
    k_graphmean<<<NGRAPHS, 256, 0, stream>>>(r, n2g, br, out, n);
}

// Round 4
// 429.401 us; speedup vs baseline: 2.3637x; 1.5722x over previous
//
#include <hip/hip_runtime.h>
#include <hip/hip_bf16.h>

#define NGRAPHS 64

// ============ CSR build ============

// count in/out degrees (int atomics)
__global__ void k_count(const int* __restrict__ src, const int* __restrict__ dst,
                        int* __restrict__ cnt_in, int* __restrict__ cnt_out, int E) {
    int e = blockIdx.x * 256 + threadIdx.x;
    if (e < E) {
        atomicAdd(&cnt_in[dst[e]], 1);
        atomicAdd(&cnt_out[src[e]], 1);
    }
}

__device__ inline int block_excl_scan(int v, int tid, int* wavesums, int* block_total) {
    // inclusive scan within wave (64)
    int lane = tid & 63, wave = tid >> 6;
    int incl = v;
    #pragma unroll
    for (int off = 1; off < 64; off <<= 1) {
        int t = __shfl_up(incl, off);
        if (lane >= off) incl += t;
    }
    if (lane == 63) wavesums[wave] = incl;
    __syncthreads();
    int woff = 0;
    #pragma unroll
    for (int w = 0; w < 4; ++w) if (w < wave) woff += wavesums[w];
    *block_total = wavesums[0] + wavesums[1] + wavesums[2] + wavesums[3];
    return incl + woff - v;  // exclusive
}

// per-block exclusive scan of cnt_in -> rowptr (block-local), block totals -> blocksums
__global__ void k_scan1(const int* __restrict__ cnt, int* __restrict__ rowptr,
                        int* __restrict__ blocksums, int n) {
    __shared__ int wavesums[4];
    int tid = threadIdx.x;
    int idx = blockIdx.x * 256 + tid;
    int v = (idx < n) ? cnt[idx] : 0;
    int total;
    int excl = block_excl_scan(v, tid, wavesums, &total);
    if (idx < n) rowptr[idx] = excl;
    if (tid == 0) blocksums[blockIdx.x] = total;
}

// single-block exclusive scan of blocksums (nb <= 256)
__global__ void k_scan2(int* __restrict__ blocksums, int nb) {
    __shared__ int wavesums[4];
    int tid = threadIdx.x;
    int v = (tid < nb) ? blocksums[tid] : 0;
    int total;
    int excl = block_excl_scan(v, tid, wavesums, &total);
    if (tid < nb) blocksums[tid] = excl;
}

// add block offsets; init cursor; write rowptr[n]
__global__ void k_scan3(int* __restrict__ rowptr, const int* __restrict__ blocksums,
                        int* __restrict__ cursor, int n, int E) {
    int idx = blockIdx.x * 256 + threadIdx.x;
    if (idx < n) {
        int v = rowptr[idx] + blocksums[blockIdx.x];
        rowptr[idx] = v;
        cursor[idx] = v;
    }
    if (idx == 0) rowptr[n] = E;
}

// fill CSR column array (src ids grouped by dst)
__global__ void k_fill(const int* __restrict__ src, const int* __restrict__ dst,
                       int* __restrict__ cursor, int* __restrict__ colsrc, int E) {
    int e = blockIdx.x * 256 + threadIdx.x;
    if (e < E) {
        int pos = atomicAdd(&cursor[dst[e]], 1);
        colsrc[pos] = src[e];
    }
}

// ============ norms + layer-0 source values ============
// norm_src=rsqrt(max(out_deg,1)), norm_dst=rsqrt(max(in_deg,1)), vsrc=in_deg*norm_src
__global__ void k_norms(const int* __restrict__ cnt_in, const int* __restrict__ cnt_out,
                        float* __restrict__ norm_src, float* __restrict__ norm_dst,
                        float* __restrict__ vsrc, int n) {
    int i = blockIdx.x * 256 + threadIdx.x;
    if (i < n) {
        float di = (float)cnt_in[i];
        float ns = rsqrtf(fmaxf((float)cnt_out[i], 1.0f));
        norm_src[i] = ns;
        norm_dst[i] = rsqrtf(fmaxf(di, 1.0f));
        vsrc[i] = di * ns;
    }
}

// ============ layer 0: scalar CSR gather ============
__global__ void k_agg0(const int* __restrict__ rowptr, const int* __restrict__ colsrc,
                       const float* __restrict__ vsrc, float* __restrict__ agg0, int n) {
    int i = blockIdx.x * 256 + threadIdx.x;
    if (i < n) {
        int p = rowptr[i], pe = rowptr[i + 1];
        float s = 0.0f;
        for (; p < pe; ++p) s += vsrc[colsrc[p]];
        agg0[i] = s;
    }
}

// layer-0 dense (rank-1): h[i][j] = relu(agg0[i]*norm_dst[i]*W0[j]+b0[j]) * norm_src[i]
__global__ void k_dense0(const float* __restrict__ agg0, const float* __restrict__ norm_dst,
                         const float* __restrict__ norm_src,
                         const float* __restrict__ W0, const float* __restrict__ b0,
                         float* __restrict__ out, int n) {
    int local = threadIdx.x >> 6, j = threadIdx.x & 63;
    int i = blockIdx.x * 4 + local;
    if (i < n) {
        float v = agg0[i] * norm_dst[i] * W0[j] + b0[j];
        out[(size_t)i * 64 + j] = fmaxf(v, 0.0f) * norm_src[i];
    }
}

// ============ fused CSR-gather aggregation + 64x64 dense ============
// wave per node: lane j gathers sum_e h[col[e]*64+j], scales by norm_dst,
// then dense via __shfl broadcast against W in LDS; relu; optional *norm_src.
__global__ void k_aggdense(const int* __restrict__ rowptr, const int* __restrict__ colsrc,
                           const float* __restrict__ hin, const float* __restrict__ norm_dst,
                           const float* __restrict__ scale_out,  // nullptr => no output scaling
                           const float* __restrict__ W, const float* __restrict__ b,
                           float* __restrict__ hout, int n) {
    __shared__ float Ws[64 * 64];
    __shared__ float bs[64];
    int tid = threadIdx.x;
    #pragma unroll
    for (int it = 0; it < 16; ++it) Ws[tid + it * 256] = W[tid + it * 256];
    if (tid < 64) bs[tid] = b[tid];
    __syncthreads();

    int wave = tid >> 6, j = tid & 63;
    int i = blockIdx.x * 4 + wave;
    if (i >= n) return;

    int p = rowptr[i], pe = rowptr[i + 1];
    float a0 = 0.0f, a1 = 0.0f, a2 = 0.0f, a3 = 0.0f;
    for (; p + 4 <= pe; p += 4) {
        int c0 = colsrc[p], c1 = colsrc[p + 1], c2 = colsrc[p + 2], c3 = colsrc[p + 3];
        a0 += hin[(size_t)c0 * 64 + j];
        a1 += hin[(size_t)c1 * 64 + j];
        a2 += hin[(size_t)c2 * 64 + j];
        a3 += hin[(size_t)c3 * 64 + j];
    }
    for (; p < pe; ++p) a0 += hin[(size_t)colsrc[p] * 64 + j];
    float a = (a0 + a1 + a2 + a3) * norm_dst[i];

    float acc = bs[j];
    #pragma unroll
    for (int k = 0; k < 64; ++k) acc = fmaf(__shfl(a, k), Ws[k * 64 + j], acc);
    acc = fmaxf(acc, 0.0f);
    if (scale_out) acc *= scale_out[i];
    hout[(size_t)i * 64 + j] = acc;
}

// ============ readout ============
__global__ void k_dot(const float* __restrict__ h, const float* __restrict__ Wr,
                      float* __restrict__ r, int n) {
    int i = blockIdx.x * 4 + (threadIdx.x >> 6);
    int j = threadIdx.x & 63;
    if (i >= n) return;
    float v = h[(size_t)i * 64 + j] * Wr[j];
    #pragma unroll
    for (int off = 32; off > 0; off >>= 1) v += __shfl_down(v, off);
    if (j == 0) r[i] = v;
}

__global__ void k_graphmean(const float* __restrict__ r, const int* __restrict__ n2g,
                            const float* __restrict__ br, float* __restrict__ out, int n) {
    __shared__ float ssum[4], scnt[4];
    int g = blockIdx.x;
    int tid = threadIdx.x;
    float s = 0.0f, c = 0.0f;
    for (int i = tid; i < n; i += 256) {
        if (n2g[i] == g) { s += r[i]; c += 1.0f; }
    }
    #pragma unroll
    for (int off = 32; off > 0; off >>= 1) {
        s += __shfl_down(s, off);
        c += __shfl_down(c, off);
    }
    int wave = tid >> 6;
    if ((tid & 63) == 0) { ssum[wave] = s; scnt[wave] = c; }
    __syncthreads();
    if (tid == 0) {
        float S = ssum[0] + ssum[1] + ssum[2] + ssum[3];
        float C = scnt[0] + scnt[1] + scnt[2] + scnt[3];
        out[g] = S / fmaxf(C, 1.0f) + br[0];
    }
}

extern "C" void kernel_launch(void* const* d_in, const int* in_sizes, int n_in,
                              void* d_out, int out_size, void* d_ws, size_t ws_size,
                              hipStream_t stream) {
    const int* src = (const int*)d_in[0];
    const int* dst = (const int*)d_in[1];
    const int* n2g = (const int*)d_in[2];
    const float* W0 = (const float*)d_in[3];
    const float* b0 = (const float*)d_in[4];
    const float* W1 = (const float*)d_in[5];
    const float* b1 = (const float*)d_in[6];
    const float* W2 = (const float*)d_in[7];
    const float* b2 = (const float*)d_in[8];
    const float* Wr = (const float*)d_in[9];
    const float* br = (const float*)d_in[10];
    float* out = (float*)d_out;

    int E = in_sizes[0];
    int n = in_sizes[2];
    int nb = (n + 255) / 256;  // 196 for n=50000; must be <= 256

    // Workspace layout:
    // ints:  [cnt_in n][cnt_out n][rowptr n+1][blocksums 256][cursor n][colsrc E]
    // floats:[norm_src n][norm_dst n][vsrc n][agg0/r n][hA 64n][hB 64n]
    int* ip = (int*)d_ws;
    int* cnt_in = ip;
    int* cnt_out = cnt_in + n;
    int* rowptr = cnt_out + n;
    int* blocksums = rowptr + (n + 1);
    int* cursor = blocksums + 256;
    int* colsrc = cursor + n;
    float* fp = (float*)(colsrc + E);
    float* norm_src = fp;
    float* norm_dst = norm_src + n;
    float* vsrc = norm_dst + n;
    float* agg0 = vsrc + n;   // reused as r for readout
    float* hA = agg0 + n;
    float* hB = hA + (size_t)n * 64;

    hipMemsetAsync(cnt_in, 0, (size_t)2 * n * sizeof(int), stream);

    // CSR build
    k_count<<<(E + 255) / 256, 256, 0, stream>>>(src, dst, cnt_in, cnt_out, E);
    k_scan1<<<nb, 256, 0, stream>>>(cnt_in, rowptr, blocksums, n);
    k_scan2<<<1, 256, 0, stream>>>(blocksums, nb);
    k_scan3<<<nb, 256, 0, stream>>>(rowptr, blocksums, cursor, n, E);
    k_fill<<<(E + 255) / 256, 256, 0, stream>>>(src, dst, cursor, colsrc, E);

    // norms + layer 0
    k_norms<<<nb, 256, 0, stream>>>(cnt_in, cnt_out, norm_src, norm_dst, vsrc, n);
    k_agg0<<<nb, 256, 0, stream>>>(rowptr, colsrc, vsrc, agg0, n);
    k_dense0<<<(n + 3) / 4, 256, 0, stream>>>(agg0, norm_dst, norm_src, W0, b0, hA, n);

    // layers 1,2: fused gather+dense
    k_aggdense<<<(n + 3) / 4, 256, 0, stream>>>(rowptr, colsrc, hA, norm_dst, norm_src, W1, b1, hB, n);
    k_aggdense<<<(n + 3) / 4, 256, 0, stream>>>(rowptr, colsrc, hB, norm_dst, nullptr, W2, b2, hA, n);

    // readout
    k_dot<<<(n + 3) / 4, 256, 0, stream>>>(hA, Wr, agg0, n);
    k_graphmean<<<NGRAPHS, 256, 0, stream>>>(agg0, n2g, br, out, n);
}

// Round 5
// 372.690 us; speedup vs baseline: 2.7233x; 1.1522x over previous
//
#include <hip/hip_runtime.h>
#include <hip/hip_bf16.h>

#define NGRAPHS 64
#define NPW 8  // nodes per wave in k_aggdense

// ============ CSR build ============

__global__ void k_count(const int* __restrict__ src, const int* __restrict__ dst,
                        int* __restrict__ cnt_in, int* __restrict__ cnt_out, int E) {
    int e = blockIdx.x * 256 + threadIdx.x;
    if (e < E) {
        atomicAdd(&cnt_in[dst[e]], 1);
        atomicAdd(&cnt_out[src[e]], 1);
    }
}

__device__ inline int block_excl_scan(int v, int tid, int* wavesums, int* block_total) {
    int lane = tid & 63, wave = tid >> 6;
    int incl = v;
    #pragma unroll
    for (int off = 1; off < 64; off <<= 1) {
        int t = __shfl_up(incl, off);
        if (lane >= off) incl += t;
    }
    if (lane == 63) wavesums[wave] = incl;
    __syncthreads();
    int woff = 0;
    #pragma unroll
    for (int w = 0; w < 4; ++w) if (w < wave) woff += wavesums[w];
    *block_total = wavesums[0] + wavesums[1] + wavesums[2] + wavesums[3];
    return incl + woff - v;
}

__global__ void k_scan1(const int* __restrict__ cnt, int* __restrict__ rowptr,
                        int* __restrict__ blocksums, int n) {
    __shared__ int wavesums[4];
    int tid = threadIdx.x;
    int idx = blockIdx.x * 256 + tid;
    int v = (idx < n) ? cnt[idx] : 0;
    int total;
    int excl = block_excl_scan(v, tid, wavesums, &total);
    if (idx < n) rowptr[idx] = excl;
    if (tid == 0) blocksums[blockIdx.x] = total;
}

__global__ void k_scan2(int* __restrict__ blocksums, int nb) {
    __shared__ int wavesums[4];
    int tid = threadIdx.x;
    int v = (tid < nb) ? blocksums[tid] : 0;
    int total;
    int excl = block_excl_scan(v, tid, wavesums, &total);
    if (tid < nb) blocksums[tid] = excl;
}

// add block offsets; init cursor; write rowptr[n]; fused norms + layer-0 source vals
__global__ void k_scan3(int* __restrict__ rowptr, const int* __restrict__ blocksums,
                        int* __restrict__ cursor,
                        const int* __restrict__ cnt_in, const int* __restrict__ cnt_out,
                        float* __restrict__ norm_src, float* __restrict__ norm_dst,
                        float* __restrict__ vsrc, int n, int E) {
    int idx = blockIdx.x * 256 + threadIdx.x;
    if (idx < n) {
        int v = rowptr[idx] + blocksums[blockIdx.x];
        rowptr[idx] = v;
        cursor[idx] = v;
        float di = (float)cnt_in[idx];
        float ns = rsqrtf(fmaxf((float)cnt_out[idx], 1.0f));
        norm_src[idx] = ns;
        norm_dst[idx] = rsqrtf(fmaxf(di, 1.0f));
        vsrc[idx] = di * ns;
    }
    if (idx == 0) rowptr[n] = E;
}

__global__ void k_fill(const int* __restrict__ src, const int* __restrict__ dst,
                       int* __restrict__ cursor, int* __restrict__ colsrc, int E) {
    int e = blockIdx.x * 256 + threadIdx.x;
    if (e < E) {
        int pos = atomicAdd(&cursor[dst[e]], 1);
        colsrc[pos] = src[e];
    }
}

// ============ layer 0: fused scalar gather + rank-1 dense ============
__global__ void k_layer0(const int* __restrict__ rowptr, const int* __restrict__ colsrc,
                         const float* __restrict__ vsrc, const float* __restrict__ norm_dst,
                         const float* __restrict__ norm_src,
                         const float* __restrict__ W0, const float* __restrict__ b0,
                         float* __restrict__ out, int n) {
    __shared__ float la[256], lns[256];
    int tid = threadIdx.x;
    int i = blockIdx.x * 256 + tid;
    if (i < n) {
        int p = rowptr[i], pe = rowptr[i + 1];
        float s0 = 0.0f, s1 = 0.0f, s2 = 0.0f, s3 = 0.0f;
        for (; p + 4 <= pe; p += 4) {
            s0 += vsrc[colsrc[p]];
            s1 += vsrc[colsrc[p + 1]];
            s2 += vsrc[colsrc[p + 2]];
            s3 += vsrc[colsrc[p + 3]];
        }
        for (; p < pe; ++p) s0 += vsrc[colsrc[p]];
        la[tid] = (s0 + s1 + s2 + s3) * norm_dst[i];
        lns[tid] = norm_src[i];
    } else {
        la[tid] = 0.0f; lns[tid] = 0.0f;
    }
    __syncthreads();
    int j = tid & 63;
    float w = W0[j], bb = b0[j];
    int nodebase = blockIdx.x * 256;
    for (int g = 0; g < 64; ++g) {
        int local = (tid >> 6) + g * 4;
        int node = nodebase + local;
        if (node < n) {
            float v = fmaxf(la[local] * w + bb, 0.0f) * lns[local];
            out[(size_t)node * 64 + j] = v;
        }
    }
}

// ============ fused CSR-gather aggregation + 64x64 dense (DS-light) ============
// Wave handles NPW nodes. W column j cached in 64 VGPRs (one-time LDS reads).
// Per node: coalesced gather, 1 ds_write of arow, 16 broadcast ds_read_b128, 64 fma.
__global__ __launch_bounds__(256, 4)
void k_aggdense(const int* __restrict__ rowptr, const int* __restrict__ colsrc,
                const float* __restrict__ hin, const float* __restrict__ norm_dst,
                const float* __restrict__ scale_out,  // nullptr => no output scaling
                const float* __restrict__ W, const float* __restrict__ b,
                float* __restrict__ hout, int n) {
    __shared__ float Ws[64 * 64];
    __shared__ float arow[4][64];
    int tid = threadIdx.x;
    #pragma unroll
    for (int it = 0; it < 16; ++it) Ws[tid + it * 256] = W[tid + it * 256];
    __syncthreads();

    int wave = tid >> 6, j = tid & 63;
    // cache W column j in registers (ds_read_b32, bank j%32 => 2-way, free)
    float wreg[64];
    #pragma unroll
    for (int k = 0; k < 64; ++k) wreg[k] = Ws[k * 64 + j];
    float bj = b[j];

    int base = (blockIdx.x * 4 + wave) * NPW;
    for (int t = 0; t < NPW; ++t) {
        int i = base + t;
        if (i >= n) break;  // uniform across wave
        int p = rowptr[i], pe = rowptr[i + 1];
        float a0 = 0.0f, a1 = 0.0f, a2 = 0.0f, a3 = 0.0f;
        for (; p + 4 <= pe; p += 4) {
            int c0 = colsrc[p], c1 = colsrc[p + 1], c2 = colsrc[p + 2], c3 = colsrc[p + 3];
            a0 += hin[(size_t)c0 * 64 + j];
            a1 += hin[(size_t)c1 * 64 + j];
            a2 += hin[(size_t)c2 * 64 + j];
            a3 += hin[(size_t)c3 * 64 + j];
        }
        for (; p < pe; ++p) a0 += hin[(size_t)colsrc[p] * 64 + j];
        arow[wave][j] = (a0 + a1 + a2 + a3) * norm_dst[i];
        // wave-synchronous LDS handoff; force write->read ordering
        asm volatile("s_waitcnt lgkmcnt(0)" ::: "memory");

        float acc = bj;
        #pragma unroll
        for (int kk = 0; kk < 16; ++kk) {
            float4 av = *(const float4*)&arow[wave][kk * 4];  // same-addr broadcast
            acc = fmaf(av.x, wreg[kk * 4 + 0], acc);
            acc = fmaf(av.y, wreg[kk * 4 + 1], acc);
            acc = fmaf(av.z, wreg[kk * 4 + 2], acc);
            acc = fmaf(av.w, wreg[kk * 4 + 3], acc);
        }
        acc = fmaxf(acc, 0.0f);
        if (scale_out) acc *= scale_out[i];
        hout[(size_t)i * 64 + j] = acc;
    }
}

// ============ readout ============
__global__ void k_dot(const float* __restrict__ h, const float* __restrict__ Wr,
                      float* __restrict__ r, int n) {
    int i = blockIdx.x * 4 + (threadIdx.x >> 6);
    int j = threadIdx.x & 63;
    if (i >= n) return;
    float v = h[(size_t)i * 64 + j] * Wr[j];
    #pragma unroll
    for (int off = 32; off > 0; off >>= 1) v += __shfl_down(v, off);
    if (j == 0) r[i] = v;
}

// n2g is sorted: binary-search graph boundaries
__global__ void k_bounds(const int* __restrict__ n2g, int* __restrict__ bnd, int n) {
    int g = threadIdx.x;
    if (g > NGRAPHS) return;
    int lo = 0, hi = n;
    while (lo < hi) {
        int mid = (lo + hi) >> 1;
        if (n2g[mid] < g) lo = mid + 1; else hi = mid;
    }
    bnd[g] = lo;
}

__global__ void k_mean(const float* __restrict__ r, const int* __restrict__ bnd,
                       const float* __restrict__ br, float* __restrict__ out) {
    __shared__ float ssum[4];
    int g = blockIdx.x;
    int lo = bnd[g], hi = bnd[g + 1];
    int tid = threadIdx.x;
    float s = 0.0f;
    for (int i = lo + tid; i < hi; i += 256) s += r[i];
    #pragma unroll
    for (int off = 32; off > 0; off >>= 1) s += __shfl_down(s, off);
    int wave = tid >> 6;
    if ((tid & 63) == 0) ssum[wave] = s;
    __syncthreads();
    if (tid == 0) {
        float S = ssum[0] + ssum[1] + ssum[2] + ssum[3];
        out[g] = S / fmaxf((float)(hi - lo), 1.0f) + br[0];
    }
}

extern "C" void kernel_launch(void* const* d_in, const int* in_sizes, int n_in,
                              void* d_out, int out_size, void* d_ws, size_t ws_size,
                              hipStream_t stream) {
    const int* src = (const int*)d_in[0];
    const int* dst = (const int*)d_in[1];
    const int* n2g = (const int*)d_in[2];
    const float* W0 = (const float*)d_in[3];
    const float* b0 = (const float*)d_in[4];
    const float* W1 = (const float*)d_in[5];
    const float* b1 = (const float*)d_in[6];
    const float* W2 = (const float*)d_in[7];
    const float* b2 = (const float*)d_in[8];
    const float* Wr = (const float*)d_in[9];
    const float* br = (const float*)d_in[10];
    float* out = (float*)d_out;

    int E = in_sizes[0];
    int n = in_sizes[2];
    int nb = (n + 255) / 256;  // 196 for n=50000; must be <= 256

    // Workspace:
    // ints:  [cnt_in n][cnt_out n][rowptr n+1][blocksums 256][cursor n][bnd 65][colsrc E]
    // floats:[norm_src n][norm_dst n][vsrc n][r n][hA 64n][hB 64n]
    int* ip = (int*)d_ws;
    int* cnt_in = ip;
    int* cnt_out = cnt_in + n;
    int* rowptr = cnt_out + n;
    int* blocksums = rowptr + (n + 1);
    int* cursor = blocksums + 256;
    int* bnd = cursor + n;
    int* colsrc = bnd + 65;
    float* fp = (float*)(colsrc + E);
    float* norm_src = fp;
    float* norm_dst = norm_src + n;
    float* vsrc = norm_dst + n;
    float* rbuf = vsrc + n;
    float* hA = rbuf + n;
    float* hB = hA + (size_t)n * 64;

    hipMemsetAsync(cnt_in, 0, (size_t)2 * n * sizeof(int), stream);

    // CSR build (+ fused norms)
    k_count<<<(E + 255) / 256, 256, 0, stream>>>(src, dst, cnt_in, cnt_out, E);
    k_scan1<<<nb, 256, 0, stream>>>(cnt_in, rowptr, blocksums, n);
    k_scan2<<<1, 256, 0, stream>>>(blocksums, nb);
    k_scan3<<<nb, 256, 0, stream>>>(rowptr, blocksums, cursor, cnt_in, cnt_out,
                                    norm_src, norm_dst, vsrc, n, E);
    k_fill<<<(E + 255) / 256, 256, 0, stream>>>(src, dst, cursor, colsrc, E);
    k_bounds<<<1, 128, 0, stream>>>(n2g, bnd, n);

    // layer 0 (fused gather + rank-1 dense)
    k_layer0<<<nb, 256, 0, stream>>>(rowptr, colsrc, vsrc, norm_dst, norm_src, W0, b0, hA, n);

    // layers 1,2: fused gather+dense
    int gad = (n + 4 * NPW - 1) / (4 * NPW);
    k_aggdense<<<gad, 256, 0, stream>>>(rowptr, colsrc, hA, norm_dst, norm_src, W1, b1, hB, n);
    k_aggdense<<<gad, 256, 0, stream>>>(rowptr, colsrc, hB, norm_dst, nullptr, W2, b2, hA, n);

    // readout
    k_dot<<<(n + 3) / 4, 256, 0, stream>>>(hA, Wr, rbuf, n);
    k_mean<<<NGRAPHS, 256, 0, stream>>>(rbuf, bnd, br, out);
}

// Round 6
// 357.878 us; speedup vs baseline: 2.8361x; 1.0414x over previous
//
#include <hip/hip_runtime.h>
#include <hip/hip_bf16.h>

#define NGRAPHS 64
#define NPW 4  // nodes per wave in k_aggdense

typedef unsigned short bf16_t;
__device__ inline float bf2f(bf16_t u) { return __uint_as_float(((unsigned)u) << 16); }
__device__ inline bf16_t f2bf(float f) {
    unsigned x = __float_as_uint(f);
    return (bf16_t)((x + 0x7fffu + ((x >> 16) & 1u)) >> 16);  // round-to-nearest-even
}

// ============ CSR build ============

__global__ void k_count(const int* __restrict__ src, const int* __restrict__ dst,
                        int* __restrict__ cnt_in, int* __restrict__ cnt_out, int E) {
    int e = blockIdx.x * 256 + threadIdx.x;
    if (e < E) {
        atomicAdd(&cnt_in[dst[e]], 1);
        atomicAdd(&cnt_out[src[e]], 1);
    }
}

__device__ inline int block_excl_scan(int v, int tid, int* wavesums, int* block_total) {
    int lane = tid & 63, wave = tid >> 6;
    int incl = v;
    #pragma unroll
    for (int off = 1; off < 64; off <<= 1) {
        int t = __shfl_up(incl, off);
        if (lane >= off) incl += t;
    }
    if (lane == 63) wavesums[wave] = incl;
    __syncthreads();
    int woff = 0;
    #pragma unroll
    for (int w = 0; w < 4; ++w) if (w < wave) woff += wavesums[w];
    *block_total = wavesums[0] + wavesums[1] + wavesums[2] + wavesums[3];
    return incl + woff - v;
}

__global__ void k_scan1(const int* __restrict__ cnt, int* __restrict__ rowptr,
                        int* __restrict__ blocksums, int n) {
    __shared__ int wavesums[4];
    int tid = threadIdx.x;
    int idx = blockIdx.x * 256 + tid;
    int v = (idx < n) ? cnt[idx] : 0;
    int total;
    int excl = block_excl_scan(v, tid, wavesums, &total);
    if (idx < n) rowptr[idx] = excl;
    if (tid == 0) blocksums[blockIdx.x] = total;
}

__global__ void k_scan2(int* __restrict__ blocksums, int nb) {
    __shared__ int wavesums[4];
    int tid = threadIdx.x;
    int v = (tid < nb) ? blocksums[tid] : 0;
    int total;
    int excl = block_excl_scan(v, tid, wavesums, &total);
    if (tid < nb) blocksums[tid] = excl;
}

// add block offsets; init cursor; write rowptr[n]; fused norms + layer-0 source vals
__global__ void k_scan3(int* __restrict__ rowptr, const int* __restrict__ blocksums,
                        int* __restrict__ cursor,
                        const int* __restrict__ cnt_in, const int* __restrict__ cnt_out,
                        float* __restrict__ norm_src, float* __restrict__ norm_dst,
                        float* __restrict__ vsrc, int n, int E) {
    int idx = blockIdx.x * 256 + threadIdx.x;
    if (idx < n) {
        int v = rowptr[idx] + blocksums[blockIdx.x];
        rowptr[idx] = v;
        cursor[idx] = v;
        float di = (float)cnt_in[idx];
        float ns = rsqrtf(fmaxf((float)cnt_out[idx], 1.0f));
        norm_src[idx] = ns;
        norm_dst[idx] = rsqrtf(fmaxf(di, 1.0f));
        vsrc[idx] = di * ns;
    }
    if (idx == 0) rowptr[n] = E;
}

__global__ void k_fill(const int* __restrict__ src, const int* __restrict__ dst,
                       int* __restrict__ cursor, int* __restrict__ colsrc, int E) {
    int e = blockIdx.x * 256 + threadIdx.x;
    if (e < E) {
        int pos = atomicAdd(&cursor[dst[e]], 1);
        colsrc[pos] = src[e];
    }
}

// ============ layer 0: wave-per-node, lane-parallel edge gather + rank-1 dense ============
__global__ void k_layer0(const int* __restrict__ rowptr, const int* __restrict__ colsrc,
                         const float* __restrict__ vsrc, const float* __restrict__ norm_dst,
                         const float* __restrict__ norm_src,
                         const float* __restrict__ W0, const float* __restrict__ b0,
                         bf16_t* __restrict__ out, int n) {
    int wave = threadIdx.x >> 6, lane = threadIdx.x & 63;
    int i = blockIdx.x * 4 + wave;
    if (i >= n) return;
    int p0 = rowptr[i], pe = rowptr[i + 1];
    float s = 0.0f;
    for (int p = p0 + lane; p < pe; p += 64) s += vsrc[colsrc[p]];
    #pragma unroll
    for (int off = 32; off > 0; off >>= 1) s += __shfl_xor(s, off);  // all lanes get sum
    float v = fmaxf(s * norm_dst[i] * W0[lane] + b0[lane], 0.0f) * norm_src[i];
    out[(size_t)i * 64 + lane] = f2bf(v);
}

// ============ fused CSR-gather aggregation + 64x64 dense ============
// bf16 h rows (128 B). W column j pinned in VGPRs via asm clobber.
// FUSE_DOT: epilogue computes r[i] = relu(acc) . Wr instead of writing hout.
template <int FUSE_DOT>
__global__ __launch_bounds__(256, 4)
void k_aggdense(const int* __restrict__ rowptr, const int* __restrict__ colsrc,
                const bf16_t* __restrict__ hin, const float* __restrict__ norm_dst,
                const float* __restrict__ scale_out,
                const float* __restrict__ W, const float* __restrict__ b,
                bf16_t* __restrict__ hout, const float* __restrict__ Wr,
                float* __restrict__ rout, int n) {
    __shared__ float Ws[64 * 64];
    __shared__ float arow[4][64];
    int tid = threadIdx.x;
    #pragma unroll
    for (int it = 0; it < 16; ++it) Ws[tid + it * 256] = W[tid + it * 256];
    __syncthreads();

    int wave = tid >> 6, j = tid & 63;
    float wreg[64];
    #pragma unroll
    for (int k = 0; k < 64; ++k) wreg[k] = Ws[k * 64 + j];
    // memory clobber: LDS reads above cannot be rematerialized past this point,
    // forcing wreg to live in VGPRs.
    asm volatile("" ::: "memory");
    float bj = b[j];

    int base = (blockIdx.x * 4 + wave) * NPW;
    for (int t = 0; t < NPW; ++t) {
        int i = base + t;
        if (i >= n) break;  // uniform across wave
        int p = rowptr[i], pe = rowptr[i + 1];
        float a0 = 0.0f, a1 = 0.0f, a2 = 0.0f, a3 = 0.0f;
        for (; p + 4 <= pe; p += 4) {
            int c0 = colsrc[p], c1 = colsrc[p + 1], c2 = colsrc[p + 2], c3 = colsrc[p + 3];
            a0 += bf2f(hin[(size_t)c0 * 64 + j]);
            a1 += bf2f(hin[(size_t)c1 * 64 + j]);
            a2 += bf2f(hin[(size_t)c2 * 64 + j]);
            a3 += bf2f(hin[(size_t)c3 * 64 + j]);
        }
        for (; p < pe; ++p) a0 += bf2f(hin[(size_t)colsrc[p] * 64 + j]);
        arow[wave][j] = (a0 + a1 + a2 + a3) * norm_dst[i];
        asm volatile("s_waitcnt lgkmcnt(0)" ::: "memory");  // wave-sync LDS handoff

        float acc = bj;
        #pragma unroll
        for (int kk = 0; kk < 16; ++kk) {
            float4 av = *(const float4*)&arow[wave][kk * 4];  // same-addr broadcast
            acc = fmaf(av.x, wreg[kk * 4 + 0], acc);
            acc = fmaf(av.y, wreg[kk * 4 + 1], acc);
            acc = fmaf(av.z, wreg[kk * 4 + 2], acc);
            acc = fmaf(av.w, wreg[kk * 4 + 3], acc);
        }
        acc = fmaxf(acc, 0.0f);
        if (FUSE_DOT) {
            float v = acc * Wr[j];
            #pragma unroll
            for (int off = 32; off > 0; off >>= 1) v += __shfl_down(v, off);
            if (j == 0) rout[i] = v;
        } else {
            acc *= scale_out[i];
            hout[(size_t)i * 64 + j] = f2bf(acc);
        }
    }
}

// ============ readout ============
__global__ void k_bounds(const int* __restrict__ n2g, int* __restrict__ bnd, int n) {
    int g = threadIdx.x;
    if (g > NGRAPHS) return;
    int lo = 0, hi = n;
    while (lo < hi) {
        int mid = (lo + hi) >> 1;
        if (n2g[mid] < g) lo = mid + 1; else hi = mid;
    }
    bnd[g] = lo;
}

__global__ void k_mean(const float* __restrict__ r, const int* __restrict__ bnd,
                       const float* __restrict__ br, float* __restrict__ out) {
    __shared__ float ssum[4];
    int g = blockIdx.x;
    int lo = bnd[g], hi = bnd[g + 1];
    int tid = threadIdx.x;
    float s = 0.0f;
    for (int i = lo + tid; i < hi; i += 256) s += r[i];
    #pragma unroll
    for (int off = 32; off > 0; off >>= 1) s += __shfl_down(s, off);
    int wave = tid >> 6;
    if ((tid & 63) == 0) ssum[wave] = s;
    __syncthreads();
    if (tid == 0) {
        float S = ssum[0] + ssum[1] + ssum[2] + ssum[3];
        out[g] = S / fmaxf((float)(hi - lo), 1.0f) + br[0];
    }
}

extern "C" void kernel_launch(void* const* d_in, const int* in_sizes, int n_in,
                              void* d_out, int out_size, void* d_ws, size_t ws_size,
                              hipStream_t stream) {
    const int* src = (const int*)d_in[0];
    const int* dst = (const int*)d_in[1];
    const int* n2g = (const int*)d_in[2];
    const float* W0 = (const float*)d_in[3];
    const float* b0 = (const float*)d_in[4];
    const float* W1 = (const float*)d_in[5];
    const float* b1 = (const float*)d_in[6];
    const float* W2 = (const float*)d_in[7];
    const float* b2 = (const float*)d_in[8];
    const float* Wr = (const float*)d_in[9];
    const float* br = (const float*)d_in[10];
    float* out = (float*)d_out;

    int E = in_sizes[0];
    int n = in_sizes[2];
    int nb = (n + 255) / 256;  // 196 for n=50000; must be <= 256

    // Workspace:
    // ints:  [cnt_in n][cnt_out n][rowptr n+1][blocksums 256][cursor n][bnd 65][colsrc E]
    // floats:[norm_src n][norm_dst n][vsrc n][r n]
    // bf16:  [hA 64n][hB 64n]
    int* ip = (int*)d_ws;
    int* cnt_in = ip;
    int* cnt_out = cnt_in + n;
    int* rowptr = cnt_out + n;
    int* blocksums = rowptr + (n + 1);
    int* cursor = blocksums + 256;
    int* bnd = cursor + n;
    int* colsrc = bnd + 65;
    float* fp = (float*)(colsrc + E);
    float* norm_src = fp;
    float* norm_dst = norm_src + n;
    float* vsrc = norm_dst + n;
    float* rbuf = vsrc + n;
    bf16_t* hA = (bf16_t*)(rbuf + n);
    bf16_t* hB = hA + (size_t)n * 64;

    hipMemsetAsync(cnt_in, 0, (size_t)2 * n * sizeof(int), stream);

    // CSR build (+ fused norms)
    k_count<<<(E + 255) / 256, 256, 0, stream>>>(src, dst, cnt_in, cnt_out, E);
    k_scan1<<<nb, 256, 0, stream>>>(cnt_in, rowptr, blocksums, n);
    k_scan2<<<1, 256, 0, stream>>>(blocksums, nb);
    k_scan3<<<nb, 256, 0, stream>>>(rowptr, blocksums, cursor, cnt_in, cnt_out,
                                    norm_src, norm_dst, vsrc, n, E);
    k_fill<<<(E + 255) / 256, 256, 0, stream>>>(src, dst, cursor, colsrc, E);
    k_bounds<<<1, 128, 0, stream>>>(n2g, bnd, n);

    // layer 0
    k_layer0<<<(n + 3) / 4, 256, 0, stream>>>(rowptr, colsrc, vsrc, norm_dst, norm_src,
                                              W0, b0, hA, n);

    // layers 1,2: fused gather+dense (layer 2 fuses the Wr dot)
    int gad = (n + 4 * NPW - 1) / (4 * NPW);
    k_aggdense<0><<<gad, 256, 0, stream>>>(rowptr, colsrc, hA, norm_dst, norm_src,
                                           W1, b1, hB, nullptr, nullptr, n);
    k_aggdense<1><<<gad, 256, 0, stream>>>(rowptr, colsrc, hB, norm_dst, nullptr,
                                           W2, b2, nullptr, Wr, rbuf, n);

    // readout
    k_mean<<<NGRAPHS, 256, 0, stream>>>(rbuf, bnd, br, out);
}

// Round 7
// 345.036 us; speedup vs baseline: 2.9416x; 1.0372x over previous
//
#include <hip/hip_runtime.h>
#include <hip/hip_bf16.h>

#define NGRAPHS 64
#define NPW 4  // nodes per wave in k_aggdense

typedef unsigned short bf16_t;
__device__ inline float bf2f(bf16_t u) { return __uint_as_float(((unsigned)u) << 16); }
__device__ inline bf16_t f2bf(float f) {
    unsigned x = __float_as_uint(f);
    return (bf16_t)((x + 0x7fffu + ((x >> 16) & 1u)) >> 16);  // round-to-nearest-even
}

// ============ CSR build ============

__global__ void k_count(const int* __restrict__ src, const int* __restrict__ dst,
                        int* __restrict__ cnt_in, int* __restrict__ cnt_out, int E) {
    int e4 = (blockIdx.x * 256 + threadIdx.x) * 4;
    if (e4 + 4 <= E) {
        int4 d = *(const int4*)&dst[e4];
        int4 s = *(const int4*)&src[e4];
        atomicAdd(&cnt_in[d.x], 1); atomicAdd(&cnt_in[d.y], 1);
        atomicAdd(&cnt_in[d.z], 1); atomicAdd(&cnt_in[d.w], 1);
        atomicAdd(&cnt_out[s.x], 1); atomicAdd(&cnt_out[s.y], 1);
        atomicAdd(&cnt_out[s.z], 1); atomicAdd(&cnt_out[s.w], 1);
    } else {
        for (int e = e4; e < E; ++e) {
            atomicAdd(&cnt_in[dst[e]], 1);
            atomicAdd(&cnt_out[src[e]], 1);
        }
    }
}

__device__ inline int block_excl_scan(int v, int tid, int* wavesums, int* block_total) {
    int lane = tid & 63, wave = tid >> 6;
    int incl = v;
    #pragma unroll
    for (int off = 1; off < 64; off <<= 1) {
        int t = __shfl_up(incl, off);
        if (lane >= off) incl += t;
    }
    if (lane == 63) wavesums[wave] = incl;
    __syncthreads();
    int woff = 0;
    #pragma unroll
    for (int w = 0; w < 4; ++w) if (w < wave) woff += wavesums[w];
    *block_total = wavesums[0] + wavesums[1] + wavesums[2] + wavesums[3];
    return incl + woff - v;
}

__global__ void k_scan1(const int* __restrict__ cnt, int* __restrict__ rowptr,
                        int* __restrict__ blocksums, int n) {
    __shared__ int wavesums[4];
    int tid = threadIdx.x;
    int idx = blockIdx.x * 256 + tid;
    int v = (idx < n) ? cnt[idx] : 0;
    int total;
    int excl = block_excl_scan(v, tid, wavesums, &total);
    if (idx < n) rowptr[idx] = excl;
    if (tid == 0) blocksums[blockIdx.x] = total;
}

__global__ void k_scan2(int* __restrict__ blocksums, int nb) {
    __shared__ int wavesums[4];
    int tid = threadIdx.x;
    int v = (tid < nb) ? blocksums[tid] : 0;
    int total;
    int excl = block_excl_scan(v, tid, wavesums, &total);
    if (tid < nb) blocksums[tid] = excl;
}

__global__ void k_scan3(int* __restrict__ rowptr, const int* __restrict__ blocksums,
                        int* __restrict__ cursor,
                        const int* __restrict__ cnt_in, const int* __restrict__ cnt_out,
                        float* __restrict__ norm_src, float* __restrict__ norm_dst,
                        float* __restrict__ vsrc, int n, int E) {
    int idx = blockIdx.x * 256 + threadIdx.x;
    if (idx < n) {
        int v = rowptr[idx] + blocksums[blockIdx.x];
        rowptr[idx] = v;
        cursor[idx] = v;
        float di = (float)cnt_in[idx];
        float ns = rsqrtf(fmaxf((float)cnt_out[idx], 1.0f));
        norm_src[idx] = ns;
        norm_dst[idx] = rsqrtf(fmaxf(di, 1.0f));
        vsrc[idx] = di * ns;
    }
    if (idx == 0) rowptr[n] = E;
}

__global__ void k_fill(const int* __restrict__ src, const int* __restrict__ dst,
                       int* __restrict__ cursor, int* __restrict__ colsrc, int E) {
    int e4 = (blockIdx.x * 256 + threadIdx.x) * 4;
    if (e4 + 4 <= E) {
        int4 d = *(const int4*)&dst[e4];
        int4 s = *(const int4*)&src[e4];
        colsrc[atomicAdd(&cursor[d.x], 1)] = s.x;
        colsrc[atomicAdd(&cursor[d.y], 1)] = s.y;
        colsrc[atomicAdd(&cursor[d.z], 1)] = s.z;
        colsrc[atomicAdd(&cursor[d.w], 1)] = s.w;
    } else {
        for (int e = e4; e < E; ++e)
            colsrc[atomicAdd(&cursor[dst[e]], 1)] = src[e];
    }
}

// ============ layer 0: wave-per-node, lane-parallel edge gather + rank-1 dense ============
__global__ void k_layer0(const int* __restrict__ rowptr, const int* __restrict__ colsrc,
                         const float* __restrict__ vsrc, const float* __restrict__ norm_dst,
                         const float* __restrict__ norm_src,
                         const float* __restrict__ W0, const float* __restrict__ b0,
                         bf16_t* __restrict__ out, int n) {
    int wave = threadIdx.x >> 6, lane = threadIdx.x & 63;
    int i = blockIdx.x * 4 + wave;
    if (i >= n) return;
    int p0 = rowptr[i], pe = rowptr[i + 1];
    float s = 0.0f;
    for (int p = p0 + lane; p < pe; p += 64) s += vsrc[colsrc[p]];
    #pragma unroll
    for (int off = 32; off > 0; off >>= 1) s += __shfl_xor(s, off);
    float v = fmaxf(s * norm_dst[i] * W0[lane] + b0[lane], 0.0f) * norm_src[i];
    out[(size_t)i * 64 + lane] = f2bf(v);
}

// ============ fused CSR-gather aggregation + 64x64 dense ============
// bf16 h rows (128 B). W column j pinned in VGPRs via volatile v_mov (non-remat).
// Gather: colsrc chunk loaded with ONE lane-parallel VMEM, uniform __shfl broadcast,
// 8 independent row-gathers per unrolled iteration.
template <int FUSE_DOT>
__global__ __launch_bounds__(256, 4)
void k_aggdense(const int* __restrict__ rowptr, const int* __restrict__ colsrc,
                const bf16_t* __restrict__ hin, const float* __restrict__ norm_dst,
                const float* __restrict__ scale_out,
                const float* __restrict__ W, const float* __restrict__ b,
                bf16_t* __restrict__ hout, const float* __restrict__ Wr,
                float* __restrict__ rout, int n) {
    __shared__ float Ws[64 * 64];
    __shared__ float arow[4][64];
    int tid = threadIdx.x;
    #pragma unroll
    for (int it = 0; it < 16; ++it) Ws[tid + it * 256] = W[tid + it * 256];
    __syncthreads();

    int wave = tid >> 6, j = tid & 63;
    // Pin W column j into 64 VGPRs: volatile asm results cannot be rematerialized.
    float wreg[64];
    #pragma unroll
    for (int k = 0; k < 64; ++k) {
        float t = Ws[k * 64 + j];
        asm volatile("v_mov_b32 %0, %1" : "=v"(wreg[k]) : "v"(t));
    }
    float bj = b[j];

    int base = (blockIdx.x * 4 + wave) * NPW;
    for (int t = 0; t < NPW; ++t) {
        int i = base + t;
        if (i >= n) break;  // uniform across wave
        int p0 = rowptr[i], deg = rowptr[i + 1] - p0;
        float a0 = 0.0f, a1 = 0.0f, a2 = 0.0f, a3 = 0.0f;
        float a4 = 0.0f, a5 = 0.0f, a6 = 0.0f, a7 = 0.0f;
        for (int cb = 0; cb < deg; cb += 64) {
            int m = min(64, deg - cb);
            int col = (j < m) ? colsrc[p0 + cb + j] : 0;  // one lane-parallel VMEM
            int e = 0;
            for (; e + 8 <= m; e += 8) {
                int c0 = __shfl(col, e + 0), c1 = __shfl(col, e + 1);
                int c2 = __shfl(col, e + 2), c3 = __shfl(col, e + 3);
                int c4 = __shfl(col, e + 4), c5 = __shfl(col, e + 5);
                int c6 = __shfl(col, e + 6), c7 = __shfl(col, e + 7);
                a0 += bf2f(hin[(size_t)c0 * 64 + j]);
                a1 += bf2f(hin[(size_t)c1 * 64 + j]);
                a2 += bf2f(hin[(size_t)c2 * 64 + j]);
                a3 += bf2f(hin[(size_t)c3 * 64 + j]);
                a4 += bf2f(hin[(size_t)c4 * 64 + j]);
                a5 += bf2f(hin[(size_t)c5 * 64 + j]);
                a6 += bf2f(hin[(size_t)c6 * 64 + j]);
                a7 += bf2f(hin[(size_t)c7 * 64 + j]);
            }
            for (; e < m; ++e) {
                int c = __shfl(col, e);
                a0 += bf2f(hin[(size_t)c * 64 + j]);
            }
        }
        arow[wave][j] = ((a0 + a1) + (a2 + a3) + ((a4 + a5) + (a6 + a7))) * norm_dst[i];
        asm volatile("s_waitcnt lgkmcnt(0)" ::: "memory");  // wave-sync LDS handoff

        float acc = bj;
        #pragma unroll
        for (int kk = 0; kk < 16; ++kk) {
            float4 av = *(const float4*)&arow[wave][kk * 4];  // same-addr broadcast
            acc = fmaf(av.x, wreg[kk * 4 + 0], acc);
            acc = fmaf(av.y, wreg[kk * 4 + 1], acc);
            acc = fmaf(av.z, wreg[kk * 4 + 2], acc);
            acc = fmaf(av.w, wreg[kk * 4 + 3], acc);
        }
        acc = fmaxf(acc, 0.0f);
        if (FUSE_DOT) {
            float v = acc * Wr[j];
            #pragma unroll
            for (int off = 32; off > 0; off >>= 1) v += __shfl_down(v, off);
            if (j == 0) rout[i] = v;
        } else {
            acc *= scale_out[i];
            hout[(size_t)i * 64 + j] = f2bf(acc);
        }
    }
}

// ============ readout ============
__global__ void k_bounds(const int* __restrict__ n2g, int* __restrict__ bnd, int n) {
    int g = threadIdx.x;
    if (g > NGRAPHS) return;
    int lo = 0, hi = n;
    while (lo < hi) {
        int mid = (lo + hi) >> 1;
        if (n2g[mid] < g) lo = mid + 1; else hi = mid;
    }
    bnd[g] = lo;
}

__global__ void k_mean(const float* __restrict__ r, const int* __restrict__ bnd,
                       const float* __restrict__ br, float* __restrict__ out) {
    __shared__ float ssum[4];
    int g = blockIdx.x;
    int lo = bnd[g], hi = bnd[g + 1];
    int tid = threadIdx.x;
    float s = 0.0f;
    for (int i = lo + tid; i < hi; i += 256) s += r[i];
    #pragma unroll
    for (int off = 32; off > 0; off >>= 1) s += __shfl_down(s, off);
    int wave = tid >> 6;
    if ((tid & 63) == 0) ssum[wave] = s;
    __syncthreads();
    if (tid == 0) {
        float S = ssum[0] + ssum[1] + ssum[2] + ssum[3];
        out[g] = S / fmaxf((float)(hi - lo), 1.0f) + br[0];
    }
}

extern "C" void kernel_launch(void* const* d_in, const int* in_sizes, int n_in,
                              void* d_out, int out_size, void* d_ws, size_t ws_size,
                              hipStream_t stream) {
    const int* src = (const int*)d_in[0];
    const int* dst = (const int*)d_in[1];
    const int* n2g = (const int*)d_in[2];
    const float* W0 = (const float*)d_in[3];
    const float* b0 = (const float*)d_in[4];
    const float* W1 = (const float*)d_in[5];
    const float* b1 = (const float*)d_in[6];
    const float* W2 = (const float*)d_in[7];
    const float* b2 = (const float*)d_in[8];
    const float* Wr = (const float*)d_in[9];
    const float* br = (const float*)d_in[10];
    float* out = (float*)d_out;

    int E = in_sizes[0];
    int n = in_sizes[2];
    int nb = (n + 255) / 256;

    int* ip = (int*)d_ws;
    int* cnt_in = ip;
    int* cnt_out = cnt_in + n;
    int* rowptr = cnt_out + n;
    int* blocksums = rowptr + (n + 1);
    int* cursor = blocksums + 256;
    int* bnd = cursor + n;
    int* colsrc = bnd + 65;
    float* fp = (float*)(colsrc + E);
    float* norm_src = fp;
    float* norm_dst = norm_src + n;
    float* vsrc = norm_dst + n;
    float* rbuf = vsrc + n;
    bf16_t* hA = (bf16_t*)(rbuf + n);
    bf16_t* hB = hA + (size_t)n * 64;

    hipMemsetAsync(cnt_in, 0, (size_t)2 * n * sizeof(int), stream);

    // CSR build (+ fused norms)
    k_count<<<(E / 4 + 255) / 256, 256, 0, stream>>>(src, dst, cnt_in, cnt_out, E);
    k_scan1<<<nb, 256, 0, stream>>>(cnt_in, rowptr, blocksums, n);
    k_scan2<<<1, 256, 0, stream>>>(blocksums, nb);
    k_scan3<<<nb, 256, 0, stream>>>(rowptr, blocksums, cursor, cnt_in, cnt_out,
                                    norm_src, norm_dst, vsrc, n, E);
    k_fill<<<(E / 4 + 255) / 256, 256, 0, stream>>>(src, dst, cursor, colsrc, E);
    k_bounds<<<1, 128, 0, stream>>>(n2g, bnd, n);

    // layer 0
    k_layer0<<<(n + 3) / 4, 256, 0, stream>>>(rowptr, colsrc, vsrc, norm_dst, norm_src,
                                              W0, b0, hA, n);

    // layers 1,2: fused gather+dense (layer 2 fuses the Wr dot)
    int gad = (n + 4 * NPW - 1) / (4 * NPW);
    k_aggdense<0><<<gad, 256, 0, stream>>>(rowptr, colsrc, hA, norm_dst, norm_src,
                                           W1, b1, hB, nullptr, nullptr, n);
    k_aggdense<1><<<gad, 256, 0, stream>>>(rowptr, colsrc, hB, norm_dst, nullptr,
                                           W2, b2, nullptr, Wr, rbuf, n);

    // readout
    k_mean<<<NGRAPHS, 256, 0, stream>>>(rbuf, bnd, br, out);
}

// Round 8
// 332.644 us; speedup vs baseline: 3.0512x; 1.0373x over previous
//
#include <hip/hip_runtime.h>
#include <hip/hip_bf16.h>

#define NGRAPHS 64
#define NPW 4   // nodes per wave in k_aggdense
#define NPART 8 // XCD-privatized copies for histogram/cursor atomics

typedef unsigned short bf16_t;
__device__ inline float bf2f(bf16_t u) { return __uint_as_float(((unsigned)u) << 16); }
__device__ inline bf16_t f2bf(float f) {
    unsigned x = __float_as_uint(f);
    return (bf16_t)((x + 0x7fffu + ((x >> 16) & 1u)) >> 16);  // round-to-nearest-even
}

// ============ CSR build (XCD-privatized atomics) ============

// count in/out degrees into per-partition copies (partition = blockIdx & 7 ~ XCD id)
__global__ void k_count(const int* __restrict__ src, const int* __restrict__ dst,
                        int* __restrict__ cnt8_in, int* __restrict__ cnt8_out, int n, int E) {
    int part = blockIdx.x & (NPART - 1);
    int* __restrict__ ci = cnt8_in + (size_t)part * n;
    int* __restrict__ co = cnt8_out + (size_t)part * n;
    int e4 = (blockIdx.x * 256 + threadIdx.x) * 4;
    if (e4 + 4 <= E) {
        int4 d = *(const int4*)&dst[e4];
        int4 s = *(const int4*)&src[e4];
        atomicAdd(&ci[d.x], 1); atomicAdd(&ci[d.y], 1);
        atomicAdd(&ci[d.z], 1); atomicAdd(&ci[d.w], 1);
        atomicAdd(&co[s.x], 1); atomicAdd(&co[s.y], 1);
        atomicAdd(&co[s.z], 1); atomicAdd(&co[s.w], 1);
    } else {
        for (int e = e4; e < E; ++e) {
            atomicAdd(&ci[dst[e]], 1);
            atomicAdd(&co[src[e]], 1);
        }
    }
}

__device__ inline int block_excl_scan(int v, int tid, int* wavesums, int* block_total) {
    int lane = tid & 63, wave = tid >> 6;
    int incl = v;
    #pragma unroll
    for (int off = 1; off < 64; off <<= 1) {
        int t = __shfl_up(incl, off);
        if (lane >= off) incl += t;
    }
    if (lane == 63) wavesums[wave] = incl;
    __syncthreads();
    int woff = 0;
    #pragma unroll
    for (int w = 0; w < 4; ++w) if (w < wave) woff += wavesums[w];
    *block_total = wavesums[0] + wavesums[1] + wavesums[2] + wavesums[3];
    return incl + woff - v;
}

// sum 8 in-count copies -> cnt_tot_in; block-local exclusive scan -> rowptr
__global__ void k_scan1(const int* __restrict__ cnt8_in, int* __restrict__ cnt_tot_in,
                        int* __restrict__ rowptr, int* __restrict__ blocksums, int n) {
    __shared__ int wavesums[4];
    int tid = threadIdx.x;
    int idx = blockIdx.x * 256 + tid;
    int v = 0;
    if (idx < n) {
        #pragma unroll
        for (int k = 0; k < NPART; ++k) v += cnt8_in[(size_t)k * n + idx];
        cnt_tot_in[idx] = v;
    }
    int total;
    int excl = block_excl_scan(v, tid, wavesums, &total);
    if (idx < n) rowptr[idx] = excl;
    if (tid == 0) blocksums[blockIdx.x] = total;
}

__global__ void k_scan2(int* __restrict__ blocksums, int nb) {
    __shared__ int wavesums[4];
    int tid = threadIdx.x;
    int v = (tid < nb) ? blocksums[tid] : 0;
    int total;
    int excl = block_excl_scan(v, tid, wavesums, &total);
    if (tid < nb) blocksums[tid] = excl;
}

// finalize rowptr; derive per-partition cursor bases; fused norms + layer-0 src vals
__global__ void k_scan3(int* __restrict__ rowptr, const int* __restrict__ blocksums,
                        const int* __restrict__ cnt8_in, const int* __restrict__ cnt8_out,
                        const int* __restrict__ cnt_tot_in,
                        int* __restrict__ cursor8,
                        float* __restrict__ norm_src, float* __restrict__ norm_dst,
                        float* __restrict__ vsrc, int n, int E) {
    int idx = blockIdx.x * 256 + threadIdx.x;
    if (idx < n) {
        int base = rowptr[idx] + blocksums[blockIdx.x];
        rowptr[idx] = base;
        int dout = 0;
        #pragma unroll
        for (int k = 0; k < NPART; ++k) {
            cursor8[(size_t)k * n + idx] = base;
            base += cnt8_in[(size_t)k * n + idx];
            dout += cnt8_out[(size_t)k * n + idx];
        }
        float di = (float)cnt_tot_in[idx];
        float ns = rsqrtf(fmaxf((float)dout, 1.0f));
        norm_src[idx] = ns;
        norm_dst[idx] = rsqrtf(fmaxf(di, 1.0f));
        vsrc[idx] = di * ns;
    }
    if (idx == 0) rowptr[n] = E;
}

// fill CSR columns using partition-local cursors
__global__ void k_fill(const int* __restrict__ src, const int* __restrict__ dst,
                       int* __restrict__ cursor8, int* __restrict__ colsrc, int n, int E) {
    int part = blockIdx.x & (NPART - 1);
    int* __restrict__ cur = cursor8 + (size_t)part * n;
    int e4 = (blockIdx.x * 256 + threadIdx.x) * 4;
    if (e4 + 4 <= E) {
        int4 d = *(const int4*)&dst[e4];
        int4 s = *(const int4*)&src[e4];
        colsrc[atomicAdd(&cur[d.x], 1)] = s.x;
        colsrc[atomicAdd(&cur[d.y], 1)] = s.y;
        colsrc[atomicAdd(&cur[d.z], 1)] = s.z;
        colsrc[atomicAdd(&cur[d.w], 1)] = s.w;
    } else {
        for (int e = e4; e < E; ++e)
            colsrc[atomicAdd(&cur[dst[e]], 1)] = src[e];
    }
}

// ============ layer 0: wave-per-node, lane-parallel edge gather + rank-1 dense ============
__global__ void k_layer0(const int* __restrict__ rowptr, const int* __restrict__ colsrc,
                         const float* __restrict__ vsrc, const float* __restrict__ norm_dst,
                         const float* __restrict__ norm_src,
                         const float* __restrict__ W0, const float* __restrict__ b0,
                         bf16_t* __restrict__ out, int n) {
    int wave = threadIdx.x >> 6, lane = threadIdx.x & 63;
    int i = blockIdx.x * 4 + wave;
    if (i >= n) return;
    int p0 = rowptr[i], pe = rowptr[i + 1];
    float s = 0.0f;
    for (int p = p0 + lane; p < pe; p += 64) s += vsrc[colsrc[p]];
    #pragma unroll
    for (int off = 32; off > 0; off >>= 1) s += __shfl_xor(s, off);
    float v = fmaxf(s * norm_dst[i] * W0[lane] + b0[lane], 0.0f) * norm_src[i];
    out[(size_t)i * 64 + lane] = f2bf(v);
}

// ============ fused CSR-gather aggregation + 64x64 dense ============
template <int FUSE_DOT>
__global__ __launch_bounds__(256, 4)
void k_aggdense(const int* __restrict__ rowptr, const int* __restrict__ colsrc,
                const bf16_t* __restrict__ hin, const float* __restrict__ norm_dst,
                const float* __restrict__ scale_out,
                const float* __restrict__ W, const float* __restrict__ b,
                bf16_t* __restrict__ hout, const float* __restrict__ Wr,
                float* __restrict__ rout, int n) {
    __shared__ float Ws[64 * 64];
    __shared__ float arow[4][64];
    int tid = threadIdx.x;
    #pragma unroll
    for (int it = 0; it < 16; ++it) Ws[tid + it * 256] = W[tid + it * 256];
    __syncthreads();

    int wave = tid >> 6, j = tid & 63;
    // Pin W column j into 64 VGPRs: volatile asm results cannot be rematerialized.
    float wreg[64];
    #pragma unroll
    for (int k = 0; k < 64; ++k) {
        float t = Ws[k * 64 + j];
        asm volatile("v_mov_b32 %0, %1" : "=v"(wreg[k]) : "v"(t));
    }
    float bj = b[j];

    int base = (blockIdx.x * 4 + wave) * NPW;
    for (int t = 0; t < NPW; ++t) {
        int i = base + t;
        if (i >= n) break;  // uniform across wave
        int p0 = rowptr[i], deg = rowptr[i + 1] - p0;
        float a0 = 0.0f, a1 = 0.0f, a2 = 0.0f, a3 = 0.0f;
        float a4 = 0.0f, a5 = 0.0f, a6 = 0.0f, a7 = 0.0f;
        for (int cb = 0; cb < deg; cb += 64) {
            int m = min(64, deg - cb);
            int col = (j < m) ? colsrc[p0 + cb + j] : 0;  // one lane-parallel VMEM
            int e = 0;
            for (; e + 8 <= m; e += 8) {
                int c0 = __shfl(col, e + 0), c1 = __shfl(col, e + 1);
                int c2 = __shfl(col, e + 2), c3 = __shfl(col, e + 3);
                int c4 = __shfl(col, e + 4), c5 = __shfl(col, e + 5);
                int c6 = __shfl(col, e + 6), c7 = __shfl(col, e + 7);
                a0 += bf2f(hin[(size_t)c0 * 64 + j]);
                a1 += bf2f(hin[(size_t)c1 * 64 + j]);
                a2 += bf2f(hin[(size_t)c2 * 64 + j]);
                a3 += bf2f(hin[(size_t)c3 * 64 + j]);
                a4 += bf2f(hin[(size_t)c4 * 64 + j]);
                a5 += bf2f(hin[(size_t)c5 * 64 + j]);
                a6 += bf2f(hin[(size_t)c6 * 64 + j]);
                a7 += bf2f(hin[(size_t)c7 * 64 + j]);
            }
            for (; e < m; ++e) {
                int c = __shfl(col, e);
                a0 += bf2f(hin[(size_t)c * 64 + j]);
            }
        }
        arow[wave][j] = ((a0 + a1) + (a2 + a3) + ((a4 + a5) + (a6 + a7))) * norm_dst[i];
        asm volatile("s_waitcnt lgkmcnt(0)" ::: "memory");  // wave-sync LDS handoff

        float acc = bj;
        #pragma unroll
        for (int kk = 0; kk < 16; ++kk) {
            float4 av = *(const float4*)&arow[wave][kk * 4];  // same-addr broadcast
            acc = fmaf(av.x, wreg[kk * 4 + 0], acc);
            acc = fmaf(av.y, wreg[kk * 4 + 1], acc);
            acc = fmaf(av.z, wreg[kk * 4 + 2], acc);
            acc = fmaf(av.w, wreg[kk * 4 + 3], acc);
        }
        acc = fmaxf(acc, 0.0f);
        if (FUSE_DOT) {
            float v = acc * Wr[j];
            #pragma unroll
            for (int off = 32; off > 0; off >>= 1) v += __shfl_down(v, off);
            if (j == 0) rout[i] = v;
        } else {
            acc *= scale_out[i];
            hout[(size_t)i * 64 + j] = f2bf(acc);
        }
    }
}

// ============ readout ============
__global__ void k_bounds(const int* __restrict__ n2g, int* __restrict__ bnd, int n) {
    int g = threadIdx.x;
    if (g > NGRAPHS) return;
    int lo = 0, hi = n;
    while (lo < hi) {
        int mid = (lo + hi) >> 1;
        if (n2g[mid] < g) lo = mid + 1; else hi = mid;
    }
    bnd[g] = lo;
}

__global__ void k_mean(const float* __restrict__ r, const int* __restrict__ bnd,
                       const float* __restrict__ br, float* __restrict__ out) {
    __shared__ float ssum[4];
    int g = blockIdx.x;
    int lo = bnd[g], hi = bnd[g + 1];
    int tid = threadIdx.x;
    float s = 0.0f;
    for (int i = lo + tid; i < hi; i += 256) s += r[i];
    #pragma unroll
    for (int off = 32; off > 0; off >>= 1) s += __shfl_down(s, off);
    int wave = tid >> 6;
    if ((tid & 63) == 0) ssum[wave] = s;
    __syncthreads();
    if (tid == 0) {
        float S = ssum[0] + ssum[1] + ssum[2] + ssum[3];
        out[g] = S / fmaxf((float)(hi - lo), 1.0f) + br[0];
    }
}

extern "C" void kernel_launch(void* const* d_in, const int* in_sizes, int n_in,
                              void* d_out, int out_size, void* d_ws, size_t ws_size,
                              hipStream_t stream) {
    const int* src = (const int*)d_in[0];
    const int* dst = (const int*)d_in[1];
    const int* n2g = (const int*)d_in[2];
    const float* W0 = (const float*)d_in[3];
    const float* b0 = (const float*)d_in[4];
    const float* W1 = (const float*)d_in[5];
    const float* b1 = (const float*)d_in[6];
    const float* W2 = (const float*)d_in[7];
    const float* b2 = (const float*)d_in[8];
    const float* Wr = (const float*)d_in[9];
    const float* br = (const float*)d_in[10];
    float* out = (float*)d_out;

    int E = in_sizes[0];
    int n = in_sizes[2];
    int nb = (n + 255) / 256;

    // Workspace:
    // ints:  [cnt8_in 8n][cnt8_out 8n][cnt_tot_in n][rowptr n+1][blocksums 256]
    //        [cursor8 8n][bnd 65][colsrc E]
    // floats:[norm_src n][norm_dst n][vsrc n][r n]
    // bf16:  [hA 64n][hB 64n]
    int* ip = (int*)d_ws;
    int* cnt8_in = ip;
    int* cnt8_out = cnt8_in + (size_t)NPART * n;
    int* cnt_tot_in = cnt8_out + (size_t)NPART * n;
    int* rowptr = cnt_tot_in + n;
    int* blocksums = rowptr + (n + 1);
    int* cursor8 = blocksums + 256;
    int* bnd = cursor8 + (size_t)NPART * n;
    int* colsrc = bnd + 65;
    float* fp = (float*)(colsrc + E);
    float* norm_src = fp;
    float* norm_dst = norm_src + n;
    float* vsrc = norm_dst + n;
    float* rbuf = vsrc + n;
    bf16_t* hA = (bf16_t*)(rbuf + n);
    bf16_t* hB = hA + (size_t)n * 64;

    hipMemsetAsync(cnt8_in, 0, (size_t)2 * NPART * n * sizeof(int), stream);

    // CSR build (+ fused norms), XCD-privatized atomics
    int gE = (E / 4 + 255) / 256;
    k_count<<<gE, 256, 0, stream>>>(src, dst, cnt8_in, cnt8_out, n, E);
    k_scan1<<<nb, 256, 0, stream>>>(cnt8_in, cnt_tot_in, rowptr, blocksums, n);
    k_scan2<<<1, 256, 0, stream>>>(blocksums, nb);
    k_scan3<<<nb, 256, 0, stream>>>(rowptr, blocksums, cnt8_in, cnt8_out, cnt_tot_in,
                                    cursor8, norm_src, norm_dst, vsrc, n, E);
    k_fill<<<gE, 256, 0, stream>>>(src, dst, cursor8, colsrc, n, E);
    k_bounds<<<1, 128, 0, stream>>>(n2g, bnd, n);

    // layer 0
    k_layer0<<<(n + 3) / 4, 256, 0, stream>>>(rowptr, colsrc, vsrc, norm_dst, norm_src,
                                              W0, b0, hA, n);

    // layers 1,2: fused gather+dense (layer 2 fuses the Wr dot)
    int gad = (n + 4 * NPW - 1) / (4 * NPW);
    k_aggdense<0><<<gad, 256, 0, stream>>>(rowptr, colsrc, hA, norm_dst, norm_src,
                                           W1, b1, hB, nullptr, nullptr, n);
    k_aggdense<1><<<gad, 256, 0, stream>>>(rowptr, colsrc, hB, norm_dst, nullptr,
                                           W2, b2, nullptr, Wr, rbuf, n);

    // readout
    k_mean<<<NGRAPHS, 256, 0, stream>>>(rbuf, bnd, br, out);
}

// Round 9
// 280.886 us; speedup vs baseline: 3.6134x; 1.1843x over previous
//
#include <hip/hip_runtime.h>
#include <hip/hip_bf16.h>

#define NGRAPHS 64
#define NPART 8 // privatized copies for histogram/cursor atomics

typedef unsigned short bf16_t;
using s8v = __attribute__((ext_vector_type(8))) short;   // 8 bf16 (4 VGPRs)
using f4v = __attribute__((ext_vector_type(4))) float;   // MFMA accumulator

__device__ inline float bf2f(bf16_t u) { return __uint_as_float(((unsigned)u) << 16); }
__device__ inline bf16_t f2bf(float f) {
    unsigned x = __float_as_uint(f);
    return (bf16_t)((x + 0x7fffu + ((x >> 16) & 1u)) >> 16);  // RNE
}

// ============ CSR build (unchanged from r8) ============

__global__ void k_count(const int* __restrict__ src, const int* __restrict__ dst,
                        int* __restrict__ cnt8_in, int* __restrict__ cnt8_out, int n, int E) {
    int part = blockIdx.x & (NPART - 1);
    int* __restrict__ ci = cnt8_in + (size_t)part * n;
    int* __restrict__ co = cnt8_out + (size_t)part * n;
    int e4 = (blockIdx.x * 256 + threadIdx.x) * 4;
    if (e4 + 4 <= E) {
        int4 d = *(const int4*)&dst[e4];
        int4 s = *(const int4*)&src[e4];
        atomicAdd(&ci[d.x], 1); atomicAdd(&ci[d.y], 1);
        atomicAdd(&ci[d.z], 1); atomicAdd(&ci[d.w], 1);
        atomicAdd(&co[s.x], 1); atomicAdd(&co[s.y], 1);
        atomicAdd(&co[s.z], 1); atomicAdd(&co[s.w], 1);
    } else {
        for (int e = e4; e < E; ++e) {
            atomicAdd(&ci[dst[e]], 1);
            atomicAdd(&co[src[e]], 1);
        }
    }
}

__device__ inline int block_excl_scan(int v, int tid, int* wavesums, int* block_total) {
    int lane = tid & 63, wave = tid >> 6;
    int incl = v;
    #pragma unroll
    for (int off = 1; off < 64; off <<= 1) {
        int t = __shfl_up(incl, off);
        if (lane >= off) incl += t;
    }
    if (lane == 63) wavesums[wave] = incl;
    __syncthreads();
    int woff = 0;
    #pragma unroll
    for (int w = 0; w < 4; ++w) if (w < wave) woff += wavesums[w];
    *block_total = wavesums[0] + wavesums[1] + wavesums[2] + wavesums[3];
    return incl + woff - v;
}

__global__ void k_scan1(const int* __restrict__ cnt8_in, int* __restrict__ cnt_tot_in,
                        int* __restrict__ rowptr, int* __restrict__ blocksums, int n) {
    __shared__ int wavesums[4];
    int tid = threadIdx.x;
    int idx = blockIdx.x * 256 + tid;
    int v = 0;
    if (idx < n) {
        #pragma unroll
        for (int k = 0; k < NPART; ++k) v += cnt8_in[(size_t)k * n + idx];
        cnt_tot_in[idx] = v;
    }
    int total;
    int excl = block_excl_scan(v, tid, wavesums, &total);
    if (idx < n) rowptr[idx] = excl;
    if (tid == 0) blocksums[blockIdx.x] = total;
}

__global__ void k_scan2(int* __restrict__ blocksums, int nb) {
    __shared__ int wavesums[4];
    int tid = threadIdx.x;
    int v = (tid < nb) ? blocksums[tid] : 0;
    int total;
    int excl = block_excl_scan(v, tid, wavesums, &total);
    if (tid < nb) blocksums[tid] = excl;
}

__global__ void k_scan3(int* __restrict__ rowptr, const int* __restrict__ blocksums,
                        const int* __restrict__ cnt8_in, const int* __restrict__ cnt8_out,
                        const int* __restrict__ cnt_tot_in,
                        int* __restrict__ cursor8,
                        float* __restrict__ norm_src, float* __restrict__ norm_dst,
                        float* __restrict__ vsrc, int n, int E) {
    int idx = blockIdx.x * 256 + threadIdx.x;
    if (idx < n) {
        int base = rowptr[idx] + blocksums[blockIdx.x];
        rowptr[idx] = base;
        int dout = 0;
        #pragma unroll
        for (int k = 0; k < NPART; ++k) {
            cursor8[(size_t)k * n + idx] = base;
            base += cnt8_in[(size_t)k * n + idx];
            dout += cnt8_out[(size_t)k * n + idx];
        }
        float di = (float)cnt_tot_in[idx];
        float ns = rsqrtf(fmaxf((float)dout, 1.0f));
        norm_src[idx] = ns;
        norm_dst[idx] = rsqrtf(fmaxf(di, 1.0f));
        vsrc[idx] = di * ns;
    }
    if (idx == 0) rowptr[n] = E;
}

__global__ void k_fill(const int* __restrict__ src, const int* __restrict__ dst,
                       int* __restrict__ cursor8, int* __restrict__ colsrc, int n, int E) {
    int part = blockIdx.x & (NPART - 1);
    int* __restrict__ cur = cursor8 + (size_t)part * n;
    int e4 = (blockIdx.x * 256 + threadIdx.x) * 4;
    if (e4 + 4 <= E) {
        int4 d = *(const int4*)&dst[e4];
        int4 s = *(const int4*)&src[e4];
        colsrc[atomicAdd(&cur[d.x], 1)] = s.x;
        colsrc[atomicAdd(&cur[d.y], 1)] = s.y;
        colsrc[atomicAdd(&cur[d.z], 1)] = s.z;
        colsrc[atomicAdd(&cur[d.w], 1)] = s.w;
    } else {
        for (int e = e4; e < E; ++e)
            colsrc[atomicAdd(&cur[dst[e]], 1)] = src[e];
    }
}

// ============ layer 0: wave-per-node gather + rank-1 dense ============
__global__ void k_layer0(const int* __restrict__ rowptr, const int* __restrict__ colsrc,
                         const float* __restrict__ vsrc, const float* __restrict__ norm_dst,
                         const float* __restrict__ norm_src,
                         const float* __restrict__ W0, const float* __restrict__ b0,
                         bf16_t* __restrict__ out, int n) {
    int wave = threadIdx.x >> 6, lane = threadIdx.x & 63;
    int i = blockIdx.x * 4 + wave;
    if (i >= n) return;
    int p0 = rowptr[i], pe = rowptr[i + 1];
    float s = 0.0f;
    for (int p = p0 + lane; p < pe; p += 64) s += vsrc[colsrc[p]];
    #pragma unroll
    for (int off = 32; off > 0; off >>= 1) s += __shfl_xor(s, off);
    float v = fmaxf(s * norm_dst[i] * W0[lane] + b0[lane], 0.0f) * norm_src[i];
    out[(size_t)i * 64 + lane] = f2bf(v);
}

// ============ pure CSR row-gather: agg[i][:] = (sum_e hin[col]) * norm_dst[i], bf16 out ============
__global__ void k_gather(const int* __restrict__ rowptr, const int* __restrict__ colsrc,
                         const bf16_t* __restrict__ hin, const float* __restrict__ norm_dst,
                         bf16_t* __restrict__ aggout, int n) {
    int wave = threadIdx.x >> 6, j = threadIdx.x & 63;
    int i = blockIdx.x * 4 + wave;
    if (i >= n) return;
    int p0 = rowptr[i], deg = rowptr[i + 1] - p0;
    float a0 = 0.0f, a1 = 0.0f, a2 = 0.0f, a3 = 0.0f;
    float a4 = 0.0f, a5 = 0.0f, a6 = 0.0f, a7 = 0.0f;
    for (int cb = 0; cb < deg; cb += 64) {
        int m = min(64, deg - cb);
        int col = (j < m) ? colsrc[p0 + cb + j] : 0;  // one lane-parallel VMEM
        int e = 0;
        for (; e + 8 <= m; e += 8) {
            int c0 = __shfl(col, e + 0), c1 = __shfl(col, e + 1);
            int c2 = __shfl(col, e + 2), c3 = __shfl(col, e + 3);
            int c4 = __shfl(col, e + 4), c5 = __shfl(col, e + 5);
            int c6 = __shfl(col, e + 6), c7 = __shfl(col, e + 7);
            a0 += bf2f(hin[(size_t)c0 * 64 + j]);
            a1 += bf2f(hin[(size_t)c1 * 64 + j]);
            a2 += bf2f(hin[(size_t)c2 * 64 + j]);
            a3 += bf2f(hin[(size_t)c3 * 64 + j]);
            a4 += bf2f(hin[(size_t)c4 * 64 + j]);
            a5 += bf2f(hin[(size_t)c5 * 64 + j]);
            a6 += bf2f(hin[(size_t)c6 * 64 + j]);
            a7 += bf2f(hin[(size_t)c7 * 64 + j]);
        }
        for (; e < m; ++e) {
            int c = __shfl(col, e);
            a0 += bf2f(hin[(size_t)c * 64 + j]);
        }
    }
    float s = (((a0 + a1) + (a2 + a3)) + ((a4 + a5) + (a6 + a7))) * norm_dst[i];
    aggout[(size_t)i * 64 + j] = f2bf(s);
}

// ============ MFMA dense: out = relu(agg @ W + b) [*norm_src | .Wr] ============
// Wave computes a 16-node strip. mfma_f32_16x16x32_bf16:
//   A-frag: A[m][k], m=lane&15, k=(lane>>4)*8+j   (verified m120)
//   B-frag: B[k][n], n=lane&15, k=(lane>>4)*8+j   (symmetric)
//   C/D:    col=lane&15, row=(lane>>4)*4+reg      (verified m89/m91)
template <int FUSE_DOT>
__global__ void k_gemm(const bf16_t* __restrict__ agg, const float* __restrict__ W,
                       const float* __restrict__ b, const float* __restrict__ norm_src,
                       const float* __restrict__ Wr,
                       bf16_t* __restrict__ hout, float* __restrict__ rout, int n) {
    __shared__ bf16_t Wbf[64 * 64];
    __shared__ float bs[64];
    int tid = threadIdx.x;
    #pragma unroll
    for (int it = 0; it < 16; ++it) {
        int idx = tid + it * 256;
        Wbf[idx] = f2bf(W[idx]);
    }
    if (tid < 64) bs[tid] = b[tid];
    __syncthreads();

    int wave = tid >> 6, lane = tid & 63;
    int quad = lane >> 4, l16 = lane & 15;

    // B fragments: W[k][f], f = t*16+l16, k = c*32 + quad*8 + jj
    s8v bfrag[4][2];
    #pragma unroll
    for (int t = 0; t < 4; ++t)
        #pragma unroll
        for (int c = 0; c < 2; ++c)
            #pragma unroll
            for (int jj = 0; jj < 8; ++jj)
                bfrag[t][c][jj] = (short)Wbf[(c * 32 + quad * 8 + jj) * 64 + t * 16 + l16];

    int m0 = (blockIdx.x * 4 + wave) * 16;
    if (m0 >= n) return;

    int arow_i = m0 + l16; if (arow_i >= n) arow_i = n - 1;
    const s8v* arow = (const s8v*)(agg + (size_t)arow_i * 64);
    s8v a0 = arow[quad];      // k in [0,32)
    s8v a1 = arow[quad + 4];  // k in [32,64)

    f4v acc[4];
    #pragma unroll
    for (int t = 0; t < 4; ++t) { acc[t][0] = 0.f; acc[t][1] = 0.f; acc[t][2] = 0.f; acc[t][3] = 0.f; }
    #pragma unroll
    for (int t = 0; t < 4; ++t) {
        acc[t] = __builtin_amdgcn_mfma_f32_16x16x32_bf16(a0, bfrag[t][0], acc[t], 0, 0, 0);
        acc[t] = __builtin_amdgcn_mfma_f32_16x16x32_bf16(a1, bfrag[t][1], acc[t], 0, 0, 0);
    }

    if (FUSE_DOT) {
        float p0 = 0.f, p1 = 0.f, p2 = 0.f, p3 = 0.f;
        #pragma unroll
        for (int t = 0; t < 4; ++t) {
            float wr = Wr[t * 16 + l16];
            float bias = bs[t * 16 + l16];
            p0 = fmaf(fmaxf(acc[t][0] + bias, 0.f), wr, p0);
            p1 = fmaf(fmaxf(acc[t][1] + bias, 0.f), wr, p1);
            p2 = fmaf(fmaxf(acc[t][2] + bias, 0.f), wr, p2);
            p3 = fmaf(fmaxf(acc[t][3] + bias, 0.f), wr, p3);
        }
        float pr[4] = {p0, p1, p2, p3};
        #pragma unroll
        for (int r = 0; r < 4; ++r) {
            float v = pr[r];
            v += __shfl_xor(v, 1); v += __shfl_xor(v, 2);
            v += __shfl_xor(v, 4); v += __shfl_xor(v, 8);
            int i = m0 + quad * 4 + r;
            if (l16 == 0 && i < n) rout[i] = v;
        }
    } else {
        float ns[4];
        #pragma unroll
        for (int r = 0; r < 4; ++r) {
            int i = m0 + quad * 4 + r;
            ns[r] = norm_src[i < n ? i : n - 1];
        }
        #pragma unroll
        for (int t = 0; t < 4; ++t) {
            float bias = bs[t * 16 + l16];
            #pragma unroll
            for (int r = 0; r < 4; ++r) {
                int i = m0 + quad * 4 + r;
                if (i < n) {
                    float v = fmaxf(acc[t][r] + bias, 0.f) * ns[r];
                    hout[(size_t)i * 64 + t * 16 + l16] = f2bf(v);
                }
            }
        }
    }
}

// ============ readout ============
__global__ void k_bounds(const int* __restrict__ n2g, int* __restrict__ bnd, int n) {
    int g = threadIdx.x;
    if (g > NGRAPHS) return;
    int lo = 0, hi = n;
    while (lo < hi) {
        int mid = (lo + hi) >> 1;
        if (n2g[mid] < g) lo = mid + 1; else hi = mid;
    }
    bnd[g] = lo;
}

__global__ void k_mean(const float* __restrict__ r, const int* __restrict__ bnd,
                       const float* __restrict__ br, float* __restrict__ out) {
    __shared__ float ssum[4];
    int g = blockIdx.x;
    int lo = bnd[g], hi = bnd[g + 1];
    int tid = threadIdx.x;
    float s = 0.0f;
    for (int i = lo + tid; i < hi; i += 256) s += r[i];
    #pragma unroll
    for (int off = 32; off > 0; off >>= 1) s += __shfl_down(s, off);
    int wave = tid >> 6;
    if ((tid & 63) == 0) ssum[wave] = s;
    __syncthreads();
    if (tid == 0) {
        float S = ssum[0] + ssum[1] + ssum[2] + ssum[3];
        out[g] = S / fmaxf((float)(hi - lo), 1.0f) + br[0];
    }
}

extern "C" void kernel_launch(void* const* d_in, const int* in_sizes, int n_in,
                              void* d_out, int out_size, void* d_ws, size_t ws_size,
                              hipStream_t stream) {
    const int* src = (const int*)d_in[0];
    const int* dst = (const int*)d_in[1];
    const int* n2g = (const int*)d_in[2];
    const float* W0 = (const float*)d_in[3];
    const float* b0 = (const float*)d_in[4];
    const float* W1 = (const float*)d_in[5];
    const float* b1 = (const float*)d_in[6];
    const float* W2 = (const float*)d_in[7];
    const float* b2 = (const float*)d_in[8];
    const float* Wr = (const float*)d_in[9];
    const float* br = (const float*)d_in[10];
    float* out = (float*)d_out;

    int E = in_sizes[0];
    int n = in_sizes[2];
    int nb = (n + 255) / 256;

    // aligned workspace carve-up
    char* base = (char*)d_ws;
    size_t off = 0;
    auto alloc = [&](size_t bytes) -> void* {
        off = (off + 255) & ~(size_t)255;
        void* p = base + off;
        off += bytes;
        return p;
    };
    int* cnt8 = (int*)alloc((size_t)2 * NPART * n * sizeof(int));
    int* cnt8_in = cnt8;
    int* cnt8_out = cnt8 + (size_t)NPART * n;
    int* cnt_tot_in = (int*)alloc((size_t)n * sizeof(int));
    int* rowptr = (int*)alloc((size_t)(n + 1) * sizeof(int));
    int* blocksums = (int*)alloc(256 * sizeof(int));
    int* cursor8 = (int*)alloc((size_t)NPART * n * sizeof(int));
    int* bnd = (int*)alloc(65 * sizeof(int));
    int* colsrc = (int*)alloc((size_t)E * sizeof(int));
    float* norm_src = (float*)alloc((size_t)n * sizeof(float));
    float* norm_dst = (float*)alloc((size_t)n * sizeof(float));
    float* vsrc = (float*)alloc((size_t)n * sizeof(float));
    float* rbuf = (float*)alloc((size_t)n * sizeof(float));
    bf16_t* hA = (bf16_t*)alloc((size_t)n * 64 * sizeof(bf16_t));
    bf16_t* hB = (bf16_t*)alloc((size_t)n * 64 * sizeof(bf16_t));
    bf16_t* aggb = (bf16_t*)alloc((size_t)n * 64 * sizeof(bf16_t));

    hipMemsetAsync(cnt8, 0, (size_t)2 * NPART * n * sizeof(int), stream);

    // CSR build (+ fused norms)
    int gE = (E / 4 + 255) / 256;
    k_count<<<gE, 256, 0, stream>>>(src, dst, cnt8_in, cnt8_out, n, E);
    k_scan1<<<nb, 256, 0, stream>>>(cnt8_in, cnt_tot_in, rowptr, blocksums, n);
    k_scan2<<<1, 256, 0, stream>>>(blocksums, nb);
    k_scan3<<<nb, 256, 0, stream>>>(rowptr, blocksums, cnt8_in, cnt8_out, cnt_tot_in,
                                    cursor8, norm_src, norm_dst, vsrc, n, E);
    k_fill<<<gE, 256, 0, stream>>>(src, dst, cursor8, colsrc, n, E);
    k_bounds<<<1, 128, 0, stream>>>(n2g, bnd, n);

    // layer 0
    k_layer0<<<(n + 3) / 4, 256, 0, stream>>>(rowptr, colsrc, vsrc, norm_dst, norm_src,
                                              W0, b0, hA, n);

    // layers 1,2: gather (latency-optimized) + MFMA dense
    int ggather = (n + 3) / 4;
    int ggemm = ((n + 15) / 16 + 3) / 4;
    k_gather<<<ggather, 256, 0, stream>>>(rowptr, colsrc, hA, norm_dst, aggb, n);
    k_gemm<0><<<ggemm, 256, 0, stream>>>(aggb, W1, b1, norm_src, nullptr, hB, nullptr, n);
    k_gather<<<ggather, 256, 0, stream>>>(rowptr, colsrc, hB, norm_dst, aggb, n);
    k_gemm<1><<<ggemm, 256, 0, stream>>>(aggb, W2, b2, nullptr, Wr, nullptr, rbuf, n);

    // readout
    k_mean<<<NGRAPHS, 256, 0, stream>>>(rbuf, bnd, br, out);
}